// Round 7
// baseline (302.587 us; speedup 1.0000x reference)
//
#include <hip/hip_runtime.h>
#include <math.h>

#define N_NODES 50000
#define N_EDGES 600000
#define BATCH 16
#define SEQ 512
#define NROWS (BATCH*SEQ)   // 8192
#define N_ITEMS (N_EDGES + N_NODES)

// ---- workspace layout (float offsets) ----
#define OFF_X      0L
#define OFF_ACC    1048576L
#define OFF_X2     2097152L
#define OFF_AS     3145728L
#define OFF_AD     3195728L
#define OFF_WC     3245728L
#define OFF_BC     3262112L
#define OFF_QP     3262240L
#define OFF_WKH    3262624L
#define OFF_CKH    3264160L
#define OFF_VAS    3264176L
#define OFF_VAD    3264304L
#define OFF_BFIN   3264432L
#define OFF_CSD    3264560L
#define OFF_VPOD   3264564L
#define OFF_UP     3266612L          // 16*8*4*128 partial u
#define OFF_SP     3332148L          // 16*8*4 partial denom
#define OFF_PWH    3332660L          // 5 matrices x 16384 ushort (packed bf16 hi)
#define OFF_PWL    3373620L          // 5 matrices x 16384 ushort (packed bf16 lo)
// ---- zeroed-every-launch block (one memset) ----
#define OFF_MASK   3414580L
#define OFF_DEG    (OFF_MASK + 50000L)
#define OFF_FILL   (OFF_DEG + 8192L)
#define OFF_CNT    (OFF_FILL + 8192L)          // [cnt, pad, pad, pad]
#define ZERO_BYTES ((50000L + 8192L + 8192L + 4L) * 4L)
// ---- end zeroed block ----
#define OFF_MAP    (OFF_CNT + 4L)
#define OFF_INV    (OFF_MAP + 50000L)
#define OFF_ROWPTR (OFF_INV + 8192L)
#define OFF_COL    (OFF_ROWPTR + 8194L)

typedef __attribute__((ext_vector_type(8))) short bf16x8;
typedef __attribute__((ext_vector_type(4))) float f32x4;
#define MFMA16(a,b,c) __builtin_amdgcn_mfma_f32_16x16x32_bf16(a,b,c,0,0,0)

__device__ __forceinline__ unsigned short f2bf_rne(float f) {
    unsigned int u = __float_as_uint(f);
    unsigned int r = u + 0x7FFFu + ((u >> 16) & 1u);
    return (unsigned short)(r >> 16);
}
__device__ __forceinline__ float bf2f(unsigned short h) {
    return __uint_as_float(((unsigned int)h) << 16);
}

// ---------------- prep: Wc = lin_W @ gat_W, bc = lin_b @ gat_W, qp for mabs 0/2/4 ----------------
__global__ __launch_bounds__(256) void prep_kernel(
    const float* __restrict__ lin_W, const float* __restrict__ lin_b,
    const float* __restrict__ gat_W,
    const float* __restrict__ mab_Wq, const float* __restrict__ mab_bq,
    const float* __restrict__ isab_I, const float* __restrict__ pma_S,
    float* __restrict__ Wc, float* __restrict__ bc, float* __restrict__ qp)
{
    int t = blockIdx.x * 256 + threadIdx.x;
    if (t < 16384) {
        int i = t >> 7, j = t & 127;
        float s = 0.f;
        for (int k = 0; k < 128; ++k) s += lin_W[i*128 + k] * gat_W[k*128 + j];
        Wc[t] = s;
    } else if (t < 16512) {
        int j = t - 16384;
        float s = 0.f;
        for (int k = 0; k < 128; ++k) s += lin_b[k] * gat_W[k*128 + j];
        bc[j] = s;
    } else if (t < 16896) {
        int u = t - 16512;
        int m = u >> 7, c = u & 127;
        int mi = m * 2;   // mab index 0, 2, 4
        const float* vec = (m == 0) ? isab_I : (m == 1 ? isab_I + 128 : pma_S);
        float s = mab_bq[mi*128 + c];
        for (int k = 0; k < 128; ++k) s += vec[k] * mab_Wq[mi*16384 + k*128 + c];
        qp[u] = s;
    }
}

// ---------------- pack2: pack 5 weight mats into MFMA B-frag order (hi/lo bf16) + wkh/ckh/vas... -
__global__ __launch_bounds__(256) void pack2_kernel(
    const float* __restrict__ Wc, const float* __restrict__ bc,
    const float* __restrict__ qp,
    const float* __restrict__ mab_Wq, const float* __restrict__ mab_Wo,
    const float* __restrict__ mab_Wk, const float* __restrict__ mab_bk,
    const float* __restrict__ att_src, const float* __restrict__ att_dst,
    const float* __restrict__ gat_bias,
    unsigned short* __restrict__ pWh, unsigned short* __restrict__ pWl,
    float* __restrict__ wkh, float* __restrict__ ckh,
    float* __restrict__ vas, float* __restrict__ vad,
    float* __restrict__ bfin, float* __restrict__ csd)
{
    int b = blockIdx.x, t = threadIdx.x;
    if (b < 320) {
        int tid = b*256 + t;             // 5*16384
        int m = tid >> 14;
        int e = tid & 16383;
        int j = e & 7, l = (e>>3) & 63, ct = (e>>9) & 7, kc = e >> 12;
        int k = kc*32 + (l>>4)*8 + j;
        int c = ct*16 + (l & 15);
        const float* src;
        if (m == 0) src = Wc;
        else if (m == 1) src = mab_Wq + 1*16384;
        else if (m == 2) src = mab_Wo + 1*16384;
        else if (m == 3) src = mab_Wq + 3*16384;
        else src = mab_Wo + 3*16384;
        float v = src[k*128 + c];
        unsigned short h = f2bf_rne(v);
        pWh[tid] = h;
        pWl[tid] = f2bf_rne(v - bf2f(h));
    } else if (b == 320) {
        for (int it = 0; it < 6; ++it) {
            int u = it*256 + t;          // 1536 wkh entries
            int m = u >> 9, h = (u >> 7) & 3, j = u & 127;
            const float* Wk = mab_Wk + (2*m)*16384 + j*128 + h*32;
            const float* q  = qp + m*128 + h*32;
            float s = 0.f;
            #pragma unroll
            for (int d = 0; d < 32; ++d) s += Wk[d] * q[d];
            wkh[u] = s;
        }
        if (t < 12) {
            int m = t >> 2, h = t & 3;
            const float* bk = mab_bk + (2*m)*128 + h*32;
            const float* q  = qp + m*128 + h*32;
            float s = 0.f;
            #pragma unroll
            for (int d = 0; d < 32; ++d) s += bk[d] * q[d];
            ckh[t] = s;
        }
    } else {
        if (t < 128) {
            float s = 0.f;
            for (int j = 0; j < 128; ++j) s += Wc[t*128 + j] * att_src[j];
            vas[t] = s;
            bfin[t] = bc[t] + gat_bias[t];
        } else {
            int k = t - 128;
            float s = 0.f;
            for (int j = 0; j < 128; ++j) s += Wc[k*128 + j] * att_dst[j];
            vad[k] = s;
        }
        if (t == 0) {
            float s = 0.f;
            for (int j = 0; j < 128; ++j) s += bc[j] * att_src[j];
            csd[0] = s;
        }
        if (t == 1) {
            float s = 0.f;
            for (int j = 0; j < 128; ++j) s += bc[j] * att_dst[j];
            csd[1] = s;
        }
    }
}

// ---------------- MFMA split-bf16 stage: acc += Xs_strip @ W  (3-term hi/lo split) --------------
__device__ __forceinline__ void mfma_stage(
    const float (*Xs)[132], int arow, int ao, int lane,
    const unsigned short* __restrict__ pWh, const unsigned short* __restrict__ pWl,
    f32x4 acc[8])
{
    #pragma unroll
    for (int kc = 0; kc < 4; ++kc) {
        float4 fa = *(const float4*)&Xs[arow][kc*32 + ao];
        float4 fb = *(const float4*)&Xs[arow][kc*32 + ao + 4];
        float f[8] = {fa.x, fa.y, fa.z, fa.w, fb.x, fb.y, fb.z, fb.w};
        bf16x8 ah, al;
        #pragma unroll
        for (int j = 0; j < 8; ++j) {
            unsigned short h = f2bf_rne(f[j]);
            ah[j] = (short)h;
            al[j] = (short)f2bf_rne(f[j] - bf2f(h));
        }
        #pragma unroll
        for (int ct = 0; ct < 8; ++ct) {
            int fo = ((kc*8 + ct)*64 + lane)*8;
            bf16x8 bh = *(const bf16x8*)(pWh + fo);
            bf16x8 bl = *(const bf16x8*)(pWl + fo);
            acc[ct] = MFMA16(ah, bh, acc[ct]);
            acc[ct] = MFMA16(ah, bl, acc[ct]);
            acc[ct] = MFMA16(al, bh, acc[ct]);
        }
    }
}

// ---------------- MFMA linear: out = Xin(8192x128) @ W + b ----------------
__global__ __launch_bounds__(256) void mfma_lin_kernel(
    const float* __restrict__ Xin,
    const unsigned short* __restrict__ pWh, const unsigned short* __restrict__ pWl,
    const float* __restrict__ b1, float* __restrict__ out)
{
    __shared__ float Xs[64][132];
    int t = threadIdx.x;
    long row0 = (long)blockIdx.x * 64;
    #pragma unroll
    for (int i = 0; i < 32; ++i) {
        int idx = i*256 + t;
        int r = idx >> 7, k = idx & 127;
        Xs[r][k] = Xin[(row0 + r)*128 + k];
    }
    __syncthreads();
    int lane = t & 63, wv = t >> 6;
    int arow = wv*16 + (lane & 15), ao = (lane >> 4)*8;
    int crow0 = wv*16 + (lane >> 4)*4, ccol = lane & 15;
    f32x4 acc[8];
    #pragma unroll
    for (int ct = 0; ct < 8; ++ct) { acc[ct][0]=0.f; acc[ct][1]=0.f; acc[ct][2]=0.f; acc[ct][3]=0.f; }
    mfma_stage(Xs, arow, ao, lane, pWh, pWl, acc);
    #pragma unroll
    for (int ct = 0; ct < 8; ++ct) {
        int cc = ct*16 + ccol;
        float bb = b1[cc];
        #pragma unroll
        for (int i = 0; i < 4; ++i)
            out[(row0 + crow0 + i)*128 + cc] = acc[ct][i] + bb;
    }
}

// ---------------- MFMA odd-MAB: O1 = X@Wq+bq+vpod[b]; Xout = O1 + relu(O1@Wo+bo) ----------------
__global__ __launch_bounds__(256) void mfma_odd_kernel(
    const float* __restrict__ Xin,
    const unsigned short* __restrict__ pQh, const unsigned short* __restrict__ pQl,
    const float* __restrict__ bq, const float* __restrict__ vpod,
    const unsigned short* __restrict__ pOh, const unsigned short* __restrict__ pOl,
    const float* __restrict__ bo, float* __restrict__ Xout)
{
    __shared__ float Xs[64][132];
    int t = threadIdx.x;
    long row0 = (long)blockIdx.x * 64;
    #pragma unroll
    for (int i = 0; i < 32; ++i) {
        int idx = i*256 + t;
        int r = idx >> 7, k = idx & 127;
        Xs[r][k] = Xin[(row0 + r)*128 + k];
    }
    __syncthreads();
    int lane = t & 63, wv = t >> 6;
    int arow = wv*16 + (lane & 15), ao = (lane >> 4)*8;
    int crow0 = wv*16 + (lane >> 4)*4, ccol = lane & 15;
    int bidx = (int)(row0 >> 9);
    f32x4 acc[8];
    #pragma unroll
    for (int ct = 0; ct < 8; ++ct) { acc[ct][0]=0.f; acc[ct][1]=0.f; acc[ct][2]=0.f; acc[ct][3]=0.f; }
    mfma_stage(Xs, arow, ao, lane, pQh, pQl, acc);
    // stage-1 epilogue into own LDS strip (wave-local rows: no block barrier needed)
    #pragma unroll
    for (int ct = 0; ct < 8; ++ct) {
        int cc = ct*16 + ccol;
        float bb = bq[cc] + vpod[bidx*128 + cc];
        #pragma unroll
        for (int i = 0; i < 4; ++i) Xs[crow0 + i][cc] = acc[ct][i] + bb;
    }
    #pragma unroll
    for (int ct = 0; ct < 8; ++ct) { acc[ct][0]=0.f; acc[ct][1]=0.f; acc[ct][2]=0.f; acc[ct][3]=0.f; }
    mfma_stage(Xs, arow, ao, lane, pOh, pOl, acc);
    #pragma unroll
    for (int ct = 0; ct < 8; ++ct) {
        int cc = ct*16 + ccol;
        float bb = bo[cc];
        #pragma unroll
        for (int i = 0; i < 4; ++i) {
            float o1 = Xs[crow0 + i][cc];
            Xout[(row0 + crow0 + i)*128 + cc] = o1 + fmaxf(acc[ct][i] + bb, 0.f);
        }
    }
}

// ---------------- per-node attention scalars (+ fused maskset in blocks 0..31) ------------------
__global__ __launch_bounds__(256) void avec_kernel(
    const float* __restrict__ embed, const float* __restrict__ vas,
    const float* __restrict__ vad, const float* __restrict__ csd,
    const int* __restrict__ node_ids, int* __restrict__ mask,
    float* __restrict__ a_s, float* __restrict__ a_d)
{
    if (blockIdx.x < 32) {
        int idx = blockIdx.x*256 + threadIdx.x;
        mask[node_ids[idx]] = 1;
    }
    int w = threadIdx.x >> 6, lane = threadIdx.x & 63;
    long row = (long)blockIdx.x * 4 + w;
    const float* xr = embed + row*128 + lane*2;
    float x0 = xr[0], x1 = xr[1];
    float s = x0*vas[lane*2] + x1*vas[lane*2 + 1];
    float d = x0*vad[lane*2] + x1*vad[lane*2 + 1];
    #pragma unroll
    for (int off = 32; off > 0; off >>= 1) {
        s += __shfl_down(s, off);
        d += __shfl_down(d, off);
    }
    if (lane == 0) { a_s[row] = s + csd[0]; a_d[row] = d + csd[1]; }
}

// ---------------- assign compact indices + inverse map (one atomic per BLOCK) -------------------
__global__ __launch_bounds__(256) void assign_kernel(
    const int* __restrict__ mask, int* __restrict__ map,
    int* __restrict__ inv, int* __restrict__ counter)
{
    __shared__ int wbase[4];
    int i = blockIdx.x*256 + threadIdx.x;
    bool act = (i < N_NODES) && mask[i];
    unsigned long long m = __ballot(act);
    int lane = threadIdx.x & 63;
    int w = threadIdx.x >> 6;
    if (lane == 0) wbase[w] = __popcll(m);
    __syncthreads();
    if (threadIdx.x == 0) {
        int tot = wbase[0] + wbase[1] + wbase[2] + wbase[3];
        int base = atomicAdd(counter, tot);
        int r = base;
        #pragma unroll
        for (int j = 0; j < 4; ++j) { int cj = wbase[j]; wbase[j] = r; r += cj; }
    }
    __syncthreads();
    if (i < N_NODES) {
        int c = -1;
        if (act) {
            c = wbase[w] + __popcll(m & ((1ull << lane) - 1ull));
            inv[c] = i;
        }
        map[i] = c;
    }
}

// ---------------- pass1: per-dest degree count (distributed atomics only) -----------------------
__global__ __launch_bounds__(256) void pass1_kernel(
    const int* __restrict__ edge_idx, const int* __restrict__ map,
    int* __restrict__ deg)
{
    int i = blockIdx.x*256 + threadIdx.x;
    if (i >= N_ITEMS) return;
    int dd = (i < N_EDGES) ? edge_idx[N_EDGES + i] : i - N_EDGES;
    int c = map[dd];
    if (c >= 0) atomicAdd(&deg[c], 1);
}

// ---------------- exclusive scan of deg[0..8191] -> rowptr[0..8192] (single block) --------------
__global__ __launch_bounds__(256) void scan_kernel(const int* __restrict__ deg,
                                                   int* __restrict__ rowptr)
{
    __shared__ int part[256];
    __shared__ int pref[256];
    int t = threadIdx.x;
    int base = t * 32;
    int s = 0;
    #pragma unroll
    for (int j = 0; j < 32; ++j) s += deg[base + j];
    part[t] = s;
    __syncthreads();
    if (t == 0) {
        int run = 0;
        for (int i = 0; i < 256; ++i) { pref[i] = run; run += part[i]; }
    }
    __syncthreads();
    int run = pref[t];
    #pragma unroll
    for (int j = 0; j < 32; ++j) { rowptr[base + j] = run; run += deg[base + j]; }
    if (t == 255) rowptr[8192] = run;
}

// ---------------- pass2: fill CSR column lists (re-reads edges, distributed atomics) ------------
__global__ __launch_bounds__(256) void pass2_kernel(
    const int* __restrict__ edge_idx, const int* __restrict__ map,
    const int* __restrict__ rowptr, int* __restrict__ fill,
    int* __restrict__ colx)
{
    int i = blockIdx.x*256 + threadIdx.x;
    if (i >= N_ITEMS) return;
    int s, dd;
    if (i < N_EDGES) { s = edge_idx[i]; dd = edge_idx[N_EDGES + i]; }
    else             { s = dd = i - N_EDGES; }
    int c = map[dd];
    if (c < 0) return;
    int pos = rowptr[c] + atomicAdd(&fill[c], 1);
    colx[pos] = s;
}

// ---------------- aggregate IN EMBED SPACE: one wave per masked destination ---------------------
__global__ __launch_bounds__(256) void agg_kernel(
    const int* __restrict__ rowptr, const int* __restrict__ colx,
    const int* __restrict__ inv, const int* __restrict__ cnt,
    const float* __restrict__ a_s, const float* __restrict__ a_d,
    const float* __restrict__ embed, float* __restrict__ acc)
{
    int c = blockIdx.x*4 + (threadIdx.x >> 6);
    int lane = threadIdx.x & 63;
    if (c >= *cnt) return;
    int dd = inv[c];
    float ad = a_d[dd];
    int beg = rowptr[c], end = rowptr[c + 1];
    float s0 = 0.f, s1 = 0.f, den = 0.f;
    for (int j = beg; j < end; ++j) {
        int s = colx[j];
        float e = a_s[s] + ad;
        e = (e > 0.f) ? e : 0.2f * e;
        float ex = __expf(e);
        den += ex;
        float2 v = *(const float2*)(embed + (long)s*128 + lane*2);
        s0 += ex * v.x;
        s1 += ex * v.y;
    }
    float inv_d = 1.f / den;
    float* o = acc + (long)c*128 + lane*2;
    o[0] = s0 * inv_d;
    o[1] = s1 * inv_d;
}

// ---------------- gather sampled node rows ----------------
__global__ __launch_bounds__(256) void gather_kernel(
    const int* __restrict__ node_ids, const int* __restrict__ map,
    const float* __restrict__ X2, float* __restrict__ X)
{
    int w = threadIdx.x >> 6, lane = threadIdx.x & 63;
    int j = blockIdx.x*4 + w;
    int c = map[node_ids[j]];
    const float2 v = *(const float2*)(X2 + (long)c*128 + lane*2);
    *(float2*)(X + (long)j*128 + lane*2) = v;
}

// ---------------- attention part A: per-64-key-chunk logits + exp + partial u/denom -------------
// grid = 16 batches x 8 chunks; no max-shift (logits provably O(0.5))
__global__ __launch_bounds__(256) void attn_partA_kernel(
    const float* __restrict__ X, const float* __restrict__ wkh,
    const float* __restrict__ ckh, float* __restrict__ up, float* __restrict__ sp)
{
    __shared__ float wks[4][128];
    __shared__ float esm[4][64];
    int b = blockIdx.x >> 3, chunk = blockIdx.x & 7;
    int t = threadIdx.x;
    #pragma unroll
    for (int i = 0; i < 2; ++i) {
        int u = i*256 + t;
        wks[u >> 7][u & 127] = wkh[u];
    }
    __syncthreads();
    const float scale = 0.088388347648318447f;  // 1/sqrt(128)
    int wv = t >> 6, lane = t & 63;
    {   // logit for key (chunk*64 + lane), head wv
        const float* xr = X + ((long)b*512 + chunk*64 + lane)*128;
        float l = 0.f;
        for (int d4 = 0; d4 < 128; d4 += 4) {
            float4 xv = *(const float4*)&xr[d4];
            l += xv.x*wks[wv][d4] + xv.y*wks[wv][d4+1]
               + xv.z*wks[wv][d4+2] + xv.w*wks[wv][d4+3];
        }
        float e = __expf((l + ckh[wv]) * scale);
        esm[wv][lane] = e;
        float s = e;
        #pragma unroll
        for (int off = 32; off > 0; off >>= 1) s += __shfl_down(s, off);
        if (lane == 0) sp[(b*8 + chunk)*4 + wv] = s;
    }
    __syncthreads();
    {   // u_part[h][d] = sum_k e[h][k] * X[k][d]  for 2 heads per thread
        int hh = t >> 7, d = t & 127;
        float a0 = 0.f, a1 = 0.f;
        const float* xc = X + ((long)b*512 + chunk*64)*128 + d;
        for (int k = 0; k < 64; ++k) {
            float xv = xc[(long)k*128];
            a0 += esm[2*hh][k] * xv;
            a1 += esm[2*hh + 1][k] * xv;
        }
        up[((b*8 + chunk)*4 + 2*hh)*128 + d] = a0;
        up[((b*8 + chunk)*4 + 2*hh + 1)*128 + d] = a1;
    }
}

// ---------------- 128x128 matvec with 512 threads (4-way split-K + LDS reduce) -----------------
__device__ __forceinline__ float matvec_qs(
    const float* __restrict__ W, const float* xs, float (*red)[128], int t)
{
    int c = t & 127, q = t >> 7;
    float acc = 0.f;
    #pragma unroll
    for (int j = 0; j < 32; ++j) {
        int k = q*32 + j;
        acc += xs[k] * W[k*128 + c];
    }
    red[q][c] = acc;
    __syncthreads();
    float s = 0.f;
    if (t < 128) s = red[0][t] + red[1][t] + red[2][t] + red[3][t];
    __syncthreads();
    return s;
}

// ---------------- even MAB finish: reduce partials, O, H, vpod (grid 16) ------------------------
__global__ __launch_bounds__(512) void attn_evenB_kernel(
    const float* __restrict__ up, const float* __restrict__ sp,
    const float* __restrict__ qp,
    const float* __restrict__ Wv, const float* __restrict__ bv,
    const float* __restrict__ Wo, const float* __restrict__ bo,
    const float* __restrict__ Wv1, const float* __restrict__ bv1,
    float* __restrict__ vpod)
{
    __shared__ float u_sm[4][128];
    __shared__ float red[4][128];
    __shared__ float qs[128], Ovec[128], Hsm[128];
    int b = blockIdx.x, t = threadIdx.x;
    if (t < 128) qs[t] = qp[t];
    {
        int h = t >> 7, d = t & 127;
        float s = 0.f, dn = 0.f;
        #pragma unroll
        for (int c = 0; c < 8; ++c) {
            s  += up[((b*8 + c)*4 + h)*128 + d];
            dn += sp[(b*8 + c)*4 + h];
        }
        u_sm[h][d] = s / dn;
    }
    __syncthreads();
    {   // O[c] = qs[c] + u_{c>>5} @ Wv[:,c] + bv[c]
        int q4 = t >> 7, c = t & 127, h = c >> 5;
        float a = 0.f;
        #pragma unroll
        for (int j = 0; j < 32; ++j) {
            int k = q4*32 + j;
            a += u_sm[h][k] * Wv[k*128 + c];
        }
        red[q4][c] = a;
    }
    __syncthreads();
    if (t < 128) Ovec[t] = qs[t] + red[0][t] + red[1][t] + red[2][t] + red[3][t] + bv[t];
    __syncthreads();
    float mv = matvec_qs(Wo, Ovec, red, t);
    if (t < 128) Hsm[t] = Ovec[t] + fmaxf(mv + bo[t], 0.f);
    __syncthreads();
    float mv2 = matvec_qs(Wv1, Hsm, red, t);
    if (t < 128) vpod[b*128 + t] = mv2 + bv1[t];
}

// ---------------- PMA finish: reduce partials + SAB + SAB + dec + prototypes (grid 16) ----------
__global__ __launch_bounds__(512) void attn_pmaB_kernel(
    const float* __restrict__ up, const float* __restrict__ sp,
    const float* __restrict__ qp,
    const float* __restrict__ mab_Wq, const float* __restrict__ mab_bq,
    const float* __restrict__ mab_Wv, const float* __restrict__ mab_bv,
    const float* __restrict__ mab_Wo, const float* __restrict__ mab_bo,
    const float* __restrict__ dec_W, const float* __restrict__ dec_b,
    const float* __restrict__ protos, float* __restrict__ out)
{
    __shared__ float u_sm[4][128];
    __shared__ float red[4][128];
    __shared__ float qs[128], Ovec[128], S1[128], S2[128];
    int b = blockIdx.x, t = threadIdx.x;
    if (t < 128) qs[t] = qp[t];
    {
        int h = t >> 7, d = t & 127;
        float s = 0.f, dn = 0.f;
        #pragma unroll
        for (int c = 0; c < 8; ++c) {
            s  += up[((b*8 + c)*4 + h)*128 + d];
            dn += sp[(b*8 + c)*4 + h];
        }
        u_sm[h][d] = s / dn;
    }
    __syncthreads();
    {
        int q4 = t >> 7, c = t & 127, h = c >> 5;
        float a = 0.f;
        #pragma unroll
        for (int j = 0; j < 32; ++j) {
            int k = q4*32 + j;
            a += u_sm[h][k] * (mab_Wv + 4*16384)[k*128 + c];
        }
        red[q4][c] = a;
    }
    __syncthreads();
    if (t < 128) Ovec[t] = qs[t] + red[0][t] + red[1][t] + red[2][t] + red[3][t]
                         + mab_bv[4*128 + t];
    __syncthreads();
    // X5 = O + relu(O@Wo4 + bo4)
    float mv = matvec_qs(mab_Wo + 4*16384, Ovec, red, t);
    if (t < 128) S1[t] = Ovec[t] + fmaxf(mv + mab_bo[4*128 + t], 0.f);
    __syncthreads();
    // SAB (mab5)
    float q5 = matvec_qs(mab_Wq + 5*16384, S1, red, t);
    float v5 = matvec_qs(mab_Wv + 5*16384, S1, red, t);
    if (t < 128) S2[t] = q5 + mab_bq[5*128 + t] + v5 + mab_bv[5*128 + t];
    __syncthreads();
    float m5 = matvec_qs(mab_Wo + 5*16384, S2, red, t);
    if (t < 128) S1[t] = S2[t] + fmaxf(m5 + mab_bo[5*128 + t], 0.f);
    __syncthreads();
    // SAB (mab6)
    float q6 = matvec_qs(mab_Wq + 6*16384, S1, red, t);
    float v6 = matvec_qs(mab_Wv + 6*16384, S1, red, t);
    if (t < 128) S2[t] = q6 + mab_bq[6*128 + t] + v6 + mab_bv[6*128 + t];
    __syncthreads();
    float m6 = matvec_qs(mab_Wo + 6*16384, S2, red, t);
    if (t < 128) S1[t] = S2[t] + fmaxf(m6 + mab_bo[6*128 + t], 0.f);
    __syncthreads();
    // dec linear
    float y = matvec_qs(dec_W, S1, red, t);
    if (t < 128) out[b*768 + t] = y + dec_b[t];
    // prototypes -> rows 1..5
    {
        int p = t >> 7, c = t & 127;
        out[b*768 + (1 + p)*128 + c] = protos[p*128 + c];
        if (t < 128) out[b*768 + 640 + t] = protos[512 + t];
    }
}

extern "C" void kernel_launch(void* const* d_in, const int* in_sizes, int n_in,
                              void* d_out, int out_size, void* d_ws, size_t ws_size,
                              hipStream_t stream)
{
    (void)in_sizes; (void)n_in; (void)out_size; (void)ws_size;
    const int*   node_ids  = (const int*)d_in[0];
    const int*   edge_idx  = (const int*)d_in[1];
    const float* node_embed= (const float*)d_in[3];
    const float* lin_W     = (const float*)d_in[4];
    const float* lin_b     = (const float*)d_in[5];
    const float* gat_W     = (const float*)d_in[6];
    const float* att_src   = (const float*)d_in[7];
    const float* att_dst   = (const float*)d_in[8];
    const float* gat_bias  = (const float*)d_in[9];
    const float* mab_Wq    = (const float*)d_in[10];
    const float* mab_bq    = (const float*)d_in[11];
    const float* mab_Wk    = (const float*)d_in[12];
    const float* mab_bk    = (const float*)d_in[13];
    const float* mab_Wv    = (const float*)d_in[14];
    const float* mab_bv    = (const float*)d_in[15];
    const float* mab_Wo    = (const float*)d_in[16];
    const float* mab_bo    = (const float*)d_in[17];
    const float* isab_I    = (const float*)d_in[18];
    const float* pma_S     = (const float*)d_in[19];
    const float* dec_W     = (const float*)d_in[20];
    const float* dec_b     = (const float*)d_in[21];
    const float* protos    = (const float*)d_in[22];

    float* ws    = (float*)d_ws;
    float* X     = ws + OFF_X;
    float* acc   = ws + OFF_ACC;
    float* X2    = ws + OFF_X2;
    float* a_s   = ws + OFF_AS;
    float* a_d   = ws + OFF_AD;
    float* Wc    = ws + OFF_WC;
    float* bc    = ws + OFF_BC;
    float* qp    = ws + OFF_QP;
    float* wkh   = ws + OFF_WKH;
    float* ckh   = ws + OFF_CKH;
    float* vas   = ws + OFF_VAS;
    float* vad   = ws + OFF_VAD;
    float* bfin  = ws + OFF_BFIN;
    float* csd   = ws + OFF_CSD;
    float* vpod  = ws + OFF_VPOD;
    float* up    = ws + OFF_UP;
    float* sp    = ws + OFF_SP;
    unsigned short* pWh = (unsigned short*)(ws + OFF_PWH);
    unsigned short* pWl = (unsigned short*)(ws + OFF_PWL);
    int*   mask  = (int*)(ws + OFF_MASK);
    int*   deg   = (int*)(ws + OFF_DEG);
    int*   fill  = (int*)(ws + OFF_FILL);
    int*   cnt   = (int*)(ws + OFF_CNT);
    int*   map   = (int*)(ws + OFF_MAP);
    int*   inv   = (int*)(ws + OFF_INV);
    int*   rowp  = (int*)(ws + OFF_ROWPTR);
    int*   colx  = (int*)(ws + OFF_COL);
    float* out   = (float*)d_out;

    hipMemsetAsync(ws + OFF_MASK, 0, ZERO_BYTES, stream);

    prep_kernel<<<66, 256, 0, stream>>>(lin_W, lin_b, gat_W, mab_Wq, mab_bq, isab_I, pma_S,
                                        Wc, bc, qp);
    pack2_kernel<<<322, 256, 0, stream>>>(Wc, bc, qp, mab_Wq, mab_Wo, mab_Wk, mab_bk,
                                          att_src, att_dst, gat_bias,
                                          pWh, pWl, wkh, ckh, vas, vad, bfin, csd);
    avec_kernel<<<N_NODES/4, 256, 0, stream>>>(node_embed, vas, vad, csd, node_ids, mask,
                                               a_s, a_d);
    assign_kernel<<<(N_NODES + 255)/256, 256, 0, stream>>>(mask, map, inv, cnt);
    pass1_kernel<<<(N_ITEMS + 255)/256, 256, 0, stream>>>(edge_idx, map, deg);
    scan_kernel<<<1, 256, 0, stream>>>(deg, rowp);
    pass2_kernel<<<(N_ITEMS + 255)/256, 256, 0, stream>>>(edge_idx, map, rowp, fill, colx);
    agg_kernel<<<NROWS/4, 256, 0, stream>>>(rowp, colx, inv, cnt, a_s, a_d, node_embed, acc);
    // X2 = acc @ Wc + (bc + gat_bias)  over compact rows  (MFMA split-bf16)
    mfma_lin_kernel<<<NROWS/64, 256, 0, stream>>>(acc, pWh, pWl, bfin, X2);
    gather_kernel<<<NROWS/4, 256, 0, stream>>>(node_ids, map, X2, X);

    for (int i = 0; i < 2; ++i) {
        int o = 2*i + 1;
        attn_partA_kernel<<<128, 256, 0, stream>>>(X, wkh + i*512, ckh + i*4, up, sp);
        attn_evenB_kernel<<<16, 512, 0, stream>>>(up, sp, qp + i*128,
                                                  mab_Wv + (2*i)*16384, mab_bv + (2*i)*128,
                                                  mab_Wo + (2*i)*16384, mab_bo + (2*i)*128,
                                                  mab_Wv + o*16384, mab_bv + o*128,
                                                  vpod);
        int mq = 1 + 2*i;     // packed slots: 1=Wq1, 2=Wo1, 3=Wq3, 4=Wo3
        int mo = 2 + 2*i;
        mfma_odd_kernel<<<NROWS/64, 256, 0, stream>>>(X,
                                                      pWh + mq*16384, pWl + mq*16384,
                                                      mab_bq + o*128, vpod,
                                                      pWh + mo*16384, pWl + mo*16384,
                                                      mab_bo + o*128, X);
    }
    attn_partA_kernel<<<128, 256, 0, stream>>>(X, wkh + 1024, ckh + 8, up, sp);
    attn_pmaB_kernel<<<16, 512, 0, stream>>>(up, sp, qp + 256,
                                             mab_Wq, mab_bq, mab_Wv, mab_bv, mab_Wo, mab_bo,
                                             dec_W, dec_b, protos, out);
}

// Round 8
// 279.114 us; speedup vs baseline: 1.0841x; 1.0841x over previous
//
#include <hip/hip_runtime.h>
#include <math.h>

#define N_NODES 50000
#define N_EDGES 600000
#define BATCH 16
#define SEQ 512
#define NROWS (BATCH*SEQ)   // 8192
#define N_ITEMS (N_EDGES + N_NODES)

// ---- workspace layout (float offsets) ----
#define OFF_X      0L
#define OFF_ACC    1048576L
#define OFF_X2     2097152L
#define OFF_AS     3145728L
#define OFF_AD     3195728L
#define OFF_WC     3245728L
#define OFF_BC     3262112L
#define OFF_QP     3262240L
#define OFF_WKH    3262624L
#define OFF_CKH    3264160L
#define OFF_VAS    3264176L
#define OFF_VAD    3264304L
#define OFF_BFIN   3264432L
#define OFF_CSD    3264560L
#define OFF_VPOD   3264564L
#define OFF_UP     3266612L          // 16*8*4*128 partial u
#define OFF_SP     3332148L          // 16*8*4 partial denom
#define OFF_PWH    3332660L          // 5 matrices x 16384 ushort (packed bf16 hi)
#define OFF_PWL    3373620L          // 5 matrices x 16384 ushort (packed bf16 lo)
// ---- zeroed-every-launch block (one memset) ----
#define OFF_MASK   3414580L
#define OFF_DEG    (OFF_MASK + 50000L)
#define OFF_FILL   (OFF_DEG + 8192L)
#define OFF_CNT    (OFF_FILL + 8192L)          // [cnt, pad, pad, pad]
#define ZERO_BYTES ((50000L + 8192L + 8192L + 4L) * 4L)
// ---- end zeroed block ----
#define OFF_MAP    (OFF_CNT + 4L)
#define OFF_INV    (OFF_MAP + 50000L)
#define OFF_ROWPTR (OFF_INV + 8192L)
#define OFF_COL    (OFF_ROWPTR + 8194L)

typedef __attribute__((ext_vector_type(8))) short bf16x8;
typedef __attribute__((ext_vector_type(4))) float f32x4;
#define MFMA16(a,b,c) __builtin_amdgcn_mfma_f32_16x16x32_bf16(a,b,c,0,0,0)

__device__ __forceinline__ unsigned short f2bf_rne(float f) {
    unsigned int u = __float_as_uint(f);
    unsigned int r = u + 0x7FFFu + ((u >> 16) & 1u);
    return (unsigned short)(r >> 16);
}
__device__ __forceinline__ float bf2f(unsigned short h) {
    return __uint_as_float(((unsigned int)h) << 16);
}

// ---------------- prep: Wc = lin_W @ gat_W, bc = lin_b @ gat_W, qp for mabs 0/2/4 ----------------
__global__ __launch_bounds__(256) void prep_kernel(
    const float* __restrict__ lin_W, const float* __restrict__ lin_b,
    const float* __restrict__ gat_W,
    const float* __restrict__ mab_Wq, const float* __restrict__ mab_bq,
    const float* __restrict__ isab_I, const float* __restrict__ pma_S,
    float* __restrict__ Wc, float* __restrict__ bc, float* __restrict__ qp)
{
    int t = blockIdx.x * 256 + threadIdx.x;
    if (t < 16384) {
        int i = t >> 7, j = t & 127;
        float s = 0.f;
        for (int k = 0; k < 128; ++k) s += lin_W[i*128 + k] * gat_W[k*128 + j];
        Wc[t] = s;
    } else if (t < 16512) {
        int j = t - 16384;
        float s = 0.f;
        for (int k = 0; k < 128; ++k) s += lin_b[k] * gat_W[k*128 + j];
        bc[j] = s;
    } else if (t < 16896) {
        int u = t - 16512;
        int m = u >> 7, c = u & 127;
        int mi = m * 2;   // mab index 0, 2, 4
        const float* vec = (m == 0) ? isab_I : (m == 1 ? isab_I + 128 : pma_S);
        float s = mab_bq[mi*128 + c];
        for (int k = 0; k < 128; ++k) s += vec[k] * mab_Wq[mi*16384 + k*128 + c];
        qp[u] = s;
    }
}

// ---------------- pack2: pack 5 weight mats into MFMA B-frag order (hi/lo bf16) + wkh/ckh/vas... -
__global__ __launch_bounds__(256) void pack2_kernel(
    const float* __restrict__ Wc, const float* __restrict__ bc,
    const float* __restrict__ qp,
    const float* __restrict__ mab_Wq, const float* __restrict__ mab_Wo,
    const float* __restrict__ mab_Wk, const float* __restrict__ mab_bk,
    const float* __restrict__ att_src, const float* __restrict__ att_dst,
    const float* __restrict__ gat_bias,
    unsigned short* __restrict__ pWh, unsigned short* __restrict__ pWl,
    float* __restrict__ wkh, float* __restrict__ ckh,
    float* __restrict__ vas, float* __restrict__ vad,
    float* __restrict__ bfin, float* __restrict__ csd)
{
    int b = blockIdx.x, t = threadIdx.x;
    if (b < 320) {
        int tid = b*256 + t;             // 5*16384
        int m = tid >> 14;
        int e = tid & 16383;
        int j = e & 7, l = (e>>3) & 63, ct = (e>>9) & 7, kc = e >> 12;
        int k = kc*32 + (l>>4)*8 + j;
        int c = ct*16 + (l & 15);
        const float* src;
        if (m == 0) src = Wc;
        else if (m == 1) src = mab_Wq + 1*16384;
        else if (m == 2) src = mab_Wo + 1*16384;
        else if (m == 3) src = mab_Wq + 3*16384;
        else src = mab_Wo + 3*16384;
        float v = src[k*128 + c];
        unsigned short h = f2bf_rne(v);
        pWh[tid] = h;
        pWl[tid] = f2bf_rne(v - bf2f(h));
    } else if (b == 320) {
        for (int it = 0; it < 6; ++it) {
            int u = it*256 + t;          // 1536 wkh entries
            int m = u >> 9, h = (u >> 7) & 3, j = u & 127;
            const float* Wk = mab_Wk + (2*m)*16384 + j*128 + h*32;
            const float* q  = qp + m*128 + h*32;
            float s = 0.f;
            #pragma unroll
            for (int d = 0; d < 32; ++d) s += Wk[d] * q[d];
            wkh[u] = s;
        }
        if (t < 12) {
            int m = t >> 2, h = t & 3;
            const float* bk = mab_bk + (2*m)*128 + h*32;
            const float* q  = qp + m*128 + h*32;
            float s = 0.f;
            #pragma unroll
            for (int d = 0; d < 32; ++d) s += bk[d] * q[d];
            ckh[t] = s;
        }
    } else {
        if (t < 128) {
            float s = 0.f;
            for (int j = 0; j < 128; ++j) s += Wc[t*128 + j] * att_src[j];
            vas[t] = s;
            bfin[t] = bc[t] + gat_bias[t];
        } else {
            int k = t - 128;
            float s = 0.f;
            for (int j = 0; j < 128; ++j) s += Wc[k*128 + j] * att_dst[j];
            vad[k] = s;
        }
        if (t == 0) {
            float s = 0.f;
            for (int j = 0; j < 128; ++j) s += bc[j] * att_src[j];
            csd[0] = s;
        }
        if (t == 1) {
            float s = 0.f;
            for (int j = 0; j < 128; ++j) s += bc[j] * att_dst[j];
            csd[1] = s;
        }
    }
}

// ---------------- MFMA split-bf16 stage: acc += Xs_strip @ W  (3-term hi/lo split) --------------
__device__ __forceinline__ void mfma_stage(
    const float (*Xs)[132], int arow, int ao, int lane,
    const unsigned short* __restrict__ pWh, const unsigned short* __restrict__ pWl,
    f32x4 acc[8])
{
    #pragma unroll
    for (int kc = 0; kc < 4; ++kc) {
        float4 fa = *(const float4*)&Xs[arow][kc*32 + ao];
        float4 fb = *(const float4*)&Xs[arow][kc*32 + ao + 4];
        float f[8] = {fa.x, fa.y, fa.z, fa.w, fb.x, fb.y, fb.z, fb.w};
        bf16x8 ah, al;
        #pragma unroll
        for (int j = 0; j < 8; ++j) {
            unsigned short h = f2bf_rne(f[j]);
            ah[j] = (short)h;
            al[j] = (short)f2bf_rne(f[j] - bf2f(h));
        }
        #pragma unroll
        for (int ct = 0; ct < 8; ++ct) {
            int fo = ((kc*8 + ct)*64 + lane)*8;
            bf16x8 bh = *(const bf16x8*)(pWh + fo);
            bf16x8 bl = *(const bf16x8*)(pWl + fo);
            acc[ct] = MFMA16(ah, bh, acc[ct]);
            acc[ct] = MFMA16(ah, bl, acc[ct]);
            acc[ct] = MFMA16(al, bh, acc[ct]);
        }
    }
}

// ---------------- MFMA linear: out = Xin(8192x128) @ W + b ----------------
__global__ __launch_bounds__(256) void mfma_lin_kernel(
    const float* __restrict__ Xin,
    const unsigned short* __restrict__ pWh, const unsigned short* __restrict__ pWl,
    const float* __restrict__ b1, float* __restrict__ out)
{
    __shared__ float Xs[64][132];
    int t = threadIdx.x;
    long row0 = (long)blockIdx.x * 64;
    #pragma unroll
    for (int i = 0; i < 32; ++i) {
        int idx = i*256 + t;
        int r = idx >> 7, k = idx & 127;
        Xs[r][k] = Xin[(row0 + r)*128 + k];
    }
    __syncthreads();
    int lane = t & 63, wv = t >> 6;
    int arow = wv*16 + (lane & 15), ao = (lane >> 4)*8;
    int crow0 = wv*16 + (lane >> 4)*4, ccol = lane & 15;
    f32x4 acc[8];
    #pragma unroll
    for (int ct = 0; ct < 8; ++ct) { acc[ct][0]=0.f; acc[ct][1]=0.f; acc[ct][2]=0.f; acc[ct][3]=0.f; }
    mfma_stage(Xs, arow, ao, lane, pWh, pWl, acc);
    #pragma unroll
    for (int ct = 0; ct < 8; ++ct) {
        int cc = ct*16 + ccol;
        float bb = b1[cc];
        #pragma unroll
        for (int i = 0; i < 4; ++i)
            out[(row0 + crow0 + i)*128 + cc] = acc[ct][i] + bb;
    }
}

// ---------------- MFMA odd-MAB: O1 = X@Wq+bq+vpod[b]; Xout = O1 + relu(O1@Wo+bo) ----------------
__global__ __launch_bounds__(256) void mfma_odd_kernel(
    const float* __restrict__ Xin,
    const unsigned short* __restrict__ pQh, const unsigned short* __restrict__ pQl,
    const float* __restrict__ bq, const float* __restrict__ vpod,
    const unsigned short* __restrict__ pOh, const unsigned short* __restrict__ pOl,
    const float* __restrict__ bo, float* __restrict__ Xout)
{
    __shared__ float Xs[64][132];
    int t = threadIdx.x;
    long row0 = (long)blockIdx.x * 64;
    #pragma unroll
    for (int i = 0; i < 32; ++i) {
        int idx = i*256 + t;
        int r = idx >> 7, k = idx & 127;
        Xs[r][k] = Xin[(row0 + r)*128 + k];
    }
    __syncthreads();
    int lane = t & 63, wv = t >> 6;
    int arow = wv*16 + (lane & 15), ao = (lane >> 4)*8;
    int crow0 = wv*16 + (lane >> 4)*4, ccol = lane & 15;
    int bidx = (int)(row0 >> 9);
    f32x4 acc[8];
    #pragma unroll
    for (int ct = 0; ct < 8; ++ct) { acc[ct][0]=0.f; acc[ct][1]=0.f; acc[ct][2]=0.f; acc[ct][3]=0.f; }
    mfma_stage(Xs, arow, ao, lane, pQh, pQl, acc);
    // stage-1 epilogue into own LDS strip (wave-local rows: no block barrier needed)
    #pragma unroll
    for (int ct = 0; ct < 8; ++ct) {
        int cc = ct*16 + ccol;
        float bb = bq[cc] + vpod[bidx*128 + cc];
        #pragma unroll
        for (int i = 0; i < 4; ++i) Xs[crow0 + i][cc] = acc[ct][i] + bb;
    }
    #pragma unroll
    for (int ct = 0; ct < 8; ++ct) { acc[ct][0]=0.f; acc[ct][1]=0.f; acc[ct][2]=0.f; acc[ct][3]=0.f; }
    mfma_stage(Xs, arow, ao, lane, pOh, pOl, acc);
    #pragma unroll
    for (int ct = 0; ct < 8; ++ct) {
        int cc = ct*16 + ccol;
        float bb = bo[cc];
        #pragma unroll
        for (int i = 0; i < 4; ++i) {
            float o1 = Xs[crow0 + i][cc];
            Xout[(row0 + crow0 + i)*128 + cc] = o1 + fmaxf(acc[ct][i] + bb, 0.f);
        }
    }
}

// ---------------- per-node attention scalars (+ fused maskset in blocks 0..31) ------------------
__global__ __launch_bounds__(256) void avec_kernel(
    const float* __restrict__ embed, const float* __restrict__ vas,
    const float* __restrict__ vad, const float* __restrict__ csd,
    const int* __restrict__ node_ids, int* __restrict__ mask,
    float* __restrict__ a_s, float* __restrict__ a_d)
{
    if (blockIdx.x < 32) {
        int idx = blockIdx.x*256 + threadIdx.x;
        mask[node_ids[idx]] = 1;
    }
    int w = threadIdx.x >> 6, lane = threadIdx.x & 63;
    long row = (long)blockIdx.x * 4 + w;
    const float* xr = embed + row*128 + lane*2;
    float x0 = xr[0], x1 = xr[1];
    float s = x0*vas[lane*2] + x1*vas[lane*2 + 1];
    float d = x0*vad[lane*2] + x1*vad[lane*2 + 1];
    #pragma unroll
    for (int off = 32; off > 0; off >>= 1) {
        s += __shfl_down(s, off);
        d += __shfl_down(d, off);
    }
    if (lane == 0) { a_s[row] = s + csd[0]; a_d[row] = d + csd[1]; }
}

// ---------------- assign compact indices + inverse map (one atomic per BLOCK) -------------------
__global__ __launch_bounds__(256) void assign_kernel(
    const int* __restrict__ mask, int* __restrict__ map,
    int* __restrict__ inv, int* __restrict__ counter)
{
    __shared__ int wbase[4];
    int i = blockIdx.x*256 + threadIdx.x;
    bool act = (i < N_NODES) && mask[i];
    unsigned long long m = __ballot(act);
    int lane = threadIdx.x & 63;
    int w = threadIdx.x >> 6;
    if (lane == 0) wbase[w] = __popcll(m);
    __syncthreads();
    if (threadIdx.x == 0) {
        int tot = wbase[0] + wbase[1] + wbase[2] + wbase[3];
        int base = atomicAdd(counter, tot);
        int r = base;
        #pragma unroll
        for (int j = 0; j < 4; ++j) { int cj = wbase[j]; wbase[j] = r; r += cj; }
    }
    __syncthreads();
    if (i < N_NODES) {
        int c = -1;
        if (act) {
            c = wbase[w] + __popcll(m & ((1ull << lane) - 1ull));
            inv[c] = i;
        }
        map[i] = c;
    }
}

// ---------------- pass1: per-dest degree count (distributed atomics only) -----------------------
__global__ __launch_bounds__(256) void pass1_kernel(
    const int* __restrict__ edge_idx, const int* __restrict__ map,
    int* __restrict__ deg)
{
    int i = blockIdx.x*256 + threadIdx.x;
    if (i >= N_ITEMS) return;
    int dd = (i < N_EDGES) ? edge_idx[N_EDGES + i] : i - N_EDGES;
    int c = map[dd];
    if (c >= 0) atomicAdd(&deg[c], 1);
}

// ---------------- exclusive scan of deg[0..8191] -> rowptr[0..8192] (single block) --------------
__global__ __launch_bounds__(256) void scan_kernel(const int* __restrict__ deg,
                                                   int* __restrict__ rowptr)
{
    __shared__ int part[256];
    __shared__ int pref[256];
    int t = threadIdx.x;
    int base = t * 32;
    int s = 0;
    #pragma unroll
    for (int j = 0; j < 32; ++j) s += deg[base + j];
    part[t] = s;
    __syncthreads();
    if (t == 0) {
        int run = 0;
        for (int i = 0; i < 256; ++i) { pref[i] = run; run += part[i]; }
    }
    __syncthreads();
    int run = pref[t];
    #pragma unroll
    for (int j = 0; j < 32; ++j) { rowptr[base + j] = run; run += deg[base + j]; }
    if (t == 255) rowptr[8192] = run;
}

// ---------------- pass2: fill CSR column lists (re-reads edges, distributed atomics) ------------
__global__ __launch_bounds__(256) void pass2_kernel(
    const int* __restrict__ edge_idx, const int* __restrict__ map,
    const int* __restrict__ rowptr, int* __restrict__ fill,
    int* __restrict__ colx)
{
    int i = blockIdx.x*256 + threadIdx.x;
    if (i >= N_ITEMS) return;
    int s, dd;
    if (i < N_EDGES) { s = edge_idx[i]; dd = edge_idx[N_EDGES + i]; }
    else             { s = dd = i - N_EDGES; }
    int c = map[dd];
    if (c < 0) return;
    int pos = rowptr[c] + atomicAdd(&fill[c], 1);
    colx[pos] = s;
}

// ---------------- aggregate IN EMBED SPACE: one wave per masked destination ---------------------
__global__ __launch_bounds__(256) void agg_kernel(
    const int* __restrict__ rowptr, const int* __restrict__ colx,
    const int* __restrict__ inv, const int* __restrict__ cnt,
    const float* __restrict__ a_s, const float* __restrict__ a_d,
    const float* __restrict__ embed, float* __restrict__ acc)
{
    int c = blockIdx.x*4 + (threadIdx.x >> 6);
    int lane = threadIdx.x & 63;
    if (c >= *cnt) return;
    int dd = inv[c];
    float ad = a_d[dd];
    int beg = rowptr[c], end = rowptr[c + 1];
    float s0 = 0.f, s1 = 0.f, den = 0.f;
    for (int j = beg; j < end; ++j) {
        int s = colx[j];
        float e = a_s[s] + ad;
        e = (e > 0.f) ? e : 0.2f * e;
        float ex = __expf(e);
        den += ex;
        float2 v = *(const float2*)(embed + (long)s*128 + lane*2);
        s0 += ex * v.x;
        s1 += ex * v.y;
    }
    float inv_d = 1.f / den;
    float* o = acc + (long)c*128 + lane*2;
    o[0] = s0 * inv_d;
    o[1] = s1 * inv_d;
}

// ---------------- gather sampled node rows ----------------
__global__ __launch_bounds__(256) void gather_kernel(
    const int* __restrict__ node_ids, const int* __restrict__ map,
    const float* __restrict__ X2, float* __restrict__ X)
{
    int w = threadIdx.x >> 6, lane = threadIdx.x & 63;
    int j = blockIdx.x*4 + w;
    int c = map[node_ids[j]];
    const float2 v = *(const float2*)(X2 + (long)c*128 + lane*2);
    *(float2*)(X + (long)j*128 + lane*2) = v;
}

// ---------------- attention part A: per-64-key-chunk logits + exp + partial u/denom -------------
// grid = 16 batches x 8 chunks; no max-shift (logits provably O(0.5))
__global__ __launch_bounds__(256) void attn_partA_kernel(
    const float* __restrict__ X, const float* __restrict__ wkh,
    const float* __restrict__ ckh, float* __restrict__ up, float* __restrict__ sp)
{
    __shared__ float wks[4][128];
    __shared__ float esm[4][64];
    int b = blockIdx.x >> 3, chunk = blockIdx.x & 7;
    int t = threadIdx.x;
    #pragma unroll
    for (int i = 0; i < 2; ++i) {
        int u = i*256 + t;
        wks[u >> 7][u & 127] = wkh[u];
    }
    __syncthreads();
    const float scale = 0.088388347648318447f;  // 1/sqrt(128)
    int wv = t >> 6, lane = t & 63;
    {   // logit for key (chunk*64 + lane), head wv
        const float* xr = X + ((long)b*512 + chunk*64 + lane)*128;
        float l = 0.f;
        for (int d4 = 0; d4 < 128; d4 += 4) {
            float4 xv = *(const float4*)&xr[d4];
            l += xv.x*wks[wv][d4] + xv.y*wks[wv][d4+1]
               + xv.z*wks[wv][d4+2] + xv.w*wks[wv][d4+3];
        }
        float e = __expf((l + ckh[wv]) * scale);
        esm[wv][lane] = e;
        float s = e;
        #pragma unroll
        for (int off = 32; off > 0; off >>= 1) s += __shfl_down(s, off);
        if (lane == 0) sp[(b*8 + chunk)*4 + wv] = s;
    }
    __syncthreads();
    {   // u_part[h][d] = sum_k e[h][k] * X[k][d]  for 2 heads per thread
        int hh = t >> 7, d = t & 127;
        float a0 = 0.f, a1 = 0.f;
        const float* xc = X + ((long)b*512 + chunk*64)*128 + d;
        for (int k = 0; k < 64; ++k) {
            float xv = xc[(long)k*128];
            a0 += esm[2*hh][k] * xv;
            a1 += esm[2*hh + 1][k] * xv;
        }
        up[((b*8 + chunk)*4 + 2*hh)*128 + d] = a0;
        up[((b*8 + chunk)*4 + 2*hh + 1)*128 + d] = a1;
    }
}

// ---------------- 128x128 matvec with 512 threads (4-way split-K + LDS reduce) -----------------
__device__ __forceinline__ float matvec_qs(
    const float* __restrict__ W, const float* xs, float (*red)[128], int t)
{
    int c = t & 127, q = t >> 7;
    float acc = 0.f;
    #pragma unroll
    for (int j = 0; j < 32; ++j) {
        int k = q*32 + j;
        acc += xs[k] * W[k*128 + c];
    }
    red[q][c] = acc;
    __syncthreads();
    float s = 0.f;
    if (t < 128) s = red[0][t] + red[1][t] + red[2][t] + red[3][t];
    __syncthreads();
    return s;
}

// ---------------- even MAB finish: warm-touch + reduce partials, O, H, vpod (grid 16) -----------
__global__ __launch_bounds__(512) void attn_evenB_kernel(
    const float* __restrict__ up, const float* __restrict__ sp,
    const float* __restrict__ qp,
    const float* __restrict__ Wv, const float* __restrict__ bv,
    const float* __restrict__ Wo, const float* __restrict__ bo,
    const float* __restrict__ Wv1, const float* __restrict__ bv1,
    float* __restrict__ vpod)
{
    __shared__ float u_sm[4][128];
    __shared__ float red[4][128];
    __shared__ float qs[128], Ovec[128], Hsm[128];
    int b = blockIdx.x, t = threadIdx.x;
    // ---- parallel warm-touch: one read per 128B line of every matrix the chain needs ----
    {
        float s = Wv[t*32] + Wo[t*32] + Wv1[t*32];
        asm volatile("" :: "v"(s));
    }
    if (t < 128) qs[t] = qp[t];
    {
        int h = t >> 7, d = t & 127;
        float s = 0.f, dn = 0.f;
        #pragma unroll
        for (int c = 0; c < 8; ++c) {
            s  += up[((b*8 + c)*4 + h)*128 + d];
            dn += sp[(b*8 + c)*4 + h];
        }
        u_sm[h][d] = s / dn;
    }
    __syncthreads();
    {   // O[c] = qs[c] + u_{c>>5} @ Wv[:,c] + bv[c]
        int q4 = t >> 7, c = t & 127, h = c >> 5;
        float a = 0.f;
        #pragma unroll
        for (int j = 0; j < 32; ++j) {
            int k = q4*32 + j;
            a += u_sm[h][k] * Wv[k*128 + c];
        }
        red[q4][c] = a;
    }
    __syncthreads();
    if (t < 128) Ovec[t] = qs[t] + red[0][t] + red[1][t] + red[2][t] + red[3][t] + bv[t];
    __syncthreads();
    float mv = matvec_qs(Wo, Ovec, red, t);
    if (t < 128) Hsm[t] = Ovec[t] + fmaxf(mv + bo[t], 0.f);
    __syncthreads();
    float mv2 = matvec_qs(Wv1, Hsm, red, t);
    if (t < 128) vpod[b*128 + t] = mv2 + bv1[t];
}

// ---------------- PMA finish: warm-touch + reduce + SAB + SAB + dec + protos (grid 16) ----------
__global__ __launch_bounds__(512) void attn_pmaB_kernel(
    const float* __restrict__ up, const float* __restrict__ sp,
    const float* __restrict__ qp,
    const float* __restrict__ mab_Wq, const float* __restrict__ mab_bq,
    const float* __restrict__ mab_Wv, const float* __restrict__ mab_bv,
    const float* __restrict__ mab_Wo, const float* __restrict__ mab_bo,
    const float* __restrict__ dec_W, const float* __restrict__ dec_b,
    const float* __restrict__ protos, float* __restrict__ out)
{
    __shared__ float u_sm[4][128];
    __shared__ float red[4][128];
    __shared__ float qs[128], Ovec[128], S1[128], S2[128];
    int b = blockIdx.x, t = threadIdx.x;
    // ---- parallel warm-touch: Wq5,Wq6 (2 mats), Wv4..6 (3), Wo4..6 (3), dec_W (1) ----
    {
        const float* wq = mab_Wq + 5*16384;
        const float* wv = mab_Wv + 4*16384;
        const float* wo = mab_Wo + 4*16384;
        float s = 0.f;
        #pragma unroll
        for (int i = 0; i < 2; ++i) s += wq[(t + 512*i)*32];
        #pragma unroll
        for (int i = 0; i < 3; ++i) { s += wv[(t + 512*i)*32]; s += wo[(t + 512*i)*32]; }
        s += dec_W[t*32];
        asm volatile("" :: "v"(s));
    }
    if (t < 128) qs[t] = qp[t];
    {
        int h = t >> 7, d = t & 127;
        float s = 0.f, dn = 0.f;
        #pragma unroll
        for (int c = 0; c < 8; ++c) {
            s  += up[((b*8 + c)*4 + h)*128 + d];
            dn += sp[(b*8 + c)*4 + h];
        }
        u_sm[h][d] = s / dn;
    }
    __syncthreads();
    {
        int q4 = t >> 7, c = t & 127, h = c >> 5;
        float a = 0.f;
        #pragma unroll
        for (int j = 0; j < 32; ++j) {
            int k = q4*32 + j;
            a += u_sm[h][k] * (mab_Wv + 4*16384)[k*128 + c];
        }
        red[q4][c] = a;
    }
    __syncthreads();
    if (t < 128) Ovec[t] = qs[t] + red[0][t] + red[1][t] + red[2][t] + red[3][t]
                         + mab_bv[4*128 + t];
    __syncthreads();
    // X5 = O + relu(O@Wo4 + bo4)
    float mv = matvec_qs(mab_Wo + 4*16384, Ovec, red, t);
    if (t < 128) S1[t] = Ovec[t] + fmaxf(mv + mab_bo[4*128 + t], 0.f);
    __syncthreads();
    // SAB (mab5)
    float q5 = matvec_qs(mab_Wq + 5*16384, S1, red, t);
    float v5 = matvec_qs(mab_Wv + 5*16384, S1, red, t);
    if (t < 128) S2[t] = q5 + mab_bq[5*128 + t] + v5 + mab_bv[5*128 + t];
    __syncthreads();
    float m5 = matvec_qs(mab_Wo + 5*16384, S2, red, t);
    if (t < 128) S1[t] = S2[t] + fmaxf(m5 + mab_bo[5*128 + t], 0.f);
    __syncthreads();
    // SAB (mab6)
    float q6 = matvec_qs(mab_Wq + 6*16384, S1, red, t);
    float v6 = matvec_qs(mab_Wv + 6*16384, S1, red, t);
    if (t < 128) S2[t] = q6 + mab_bq[6*128 + t] + v6 + mab_bv[6*128 + t];
    __syncthreads();
    float m6 = matvec_qs(mab_Wo + 6*16384, S2, red, t);
    if (t < 128) S1[t] = S2[t] + fmaxf(m6 + mab_bo[6*128 + t], 0.f);
    __syncthreads();
    // dec linear
    float y = matvec_qs(dec_W, S1, red, t);
    if (t < 128) out[b*768 + t] = y + dec_b[t];
    // prototypes -> rows 1..5
    {
        int p = t >> 7, c = t & 127;
        out[b*768 + (1 + p)*128 + c] = protos[p*128 + c];
        if (t < 128) out[b*768 + 640 + t] = protos[512 + t];
    }
}

extern "C" void kernel_launch(void* const* d_in, const int* in_sizes, int n_in,
                              void* d_out, int out_size, void* d_ws, size_t ws_size,
                              hipStream_t stream)
{
    (void)in_sizes; (void)n_in; (void)out_size; (void)ws_size;
    const int*   node_ids  = (const int*)d_in[0];
    const int*   edge_idx  = (const int*)d_in[1];
    const float* node_embed= (const float*)d_in[3];
    const float* lin_W     = (const float*)d_in[4];
    const float* lin_b     = (const float*)d_in[5];
    const float* gat_W     = (const float*)d_in[6];
    const float* att_src   = (const float*)d_in[7];
    const float* att_dst   = (const float*)d_in[8];
    const float* gat_bias  = (const float*)d_in[9];
    const float* mab_Wq    = (const float*)d_in[10];
    const float* mab_bq    = (const float*)d_in[11];
    const float* mab_Wk    = (const float*)d_in[12];
    const float* mab_bk    = (const float*)d_in[13];
    const float* mab_Wv    = (const float*)d_in[14];
    const float* mab_bv    = (const float*)d_in[15];
    const float* mab_Wo    = (const float*)d_in[16];
    const float* mab_bo    = (const float*)d_in[17];
    const float* isab_I    = (const float*)d_in[18];
    const float* pma_S     = (const float*)d_in[19];
    const float* dec_W     = (const float*)d_in[20];
    const float* dec_b     = (const float*)d_in[21];
    const float* protos    = (const float*)d_in[22];

    float* ws    = (float*)d_ws;
    float* X     = ws + OFF_X;
    float* acc   = ws + OFF_ACC;
    float* X2    = ws + OFF_X2;
    float* a_s   = ws + OFF_AS;
    float* a_d   = ws + OFF_AD;
    float* Wc    = ws + OFF_WC;
    float* bc    = ws + OFF_BC;
    float* qp    = ws + OFF_QP;
    float* wkh   = ws + OFF_WKH;
    float* ckh   = ws + OFF_CKH;
    float* vas   = ws + OFF_VAS;
    float* vad   = ws + OFF_VAD;
    float* bfin  = ws + OFF_BFIN;
    float* csd   = ws + OFF_CSD;
    float* vpod  = ws + OFF_VPOD;
    float* up    = ws + OFF_UP;
    float* sp    = ws + OFF_SP;
    unsigned short* pWh = (unsigned short*)(ws + OFF_PWH);
    unsigned short* pWl = (unsigned short*)(ws + OFF_PWL);
    int*   mask  = (int*)(ws + OFF_MASK);
    int*   deg   = (int*)(ws + OFF_DEG);
    int*   fill  = (int*)(ws + OFF_FILL);
    int*   cnt   = (int*)(ws + OFF_CNT);
    int*   map   = (int*)(ws + OFF_MAP);
    int*   inv   = (int*)(ws + OFF_INV);
    int*   rowp  = (int*)(ws + OFF_ROWPTR);
    int*   colx  = (int*)(ws + OFF_COL);
    float* out   = (float*)d_out;

    hipMemsetAsync(ws + OFF_MASK, 0, ZERO_BYTES, stream);

    prep_kernel<<<66, 256, 0, stream>>>(lin_W, lin_b, gat_W, mab_Wq, mab_bq, isab_I, pma_S,
                                        Wc, bc, qp);
    pack2_kernel<<<322, 256, 0, stream>>>(Wc, bc, qp, mab_Wq, mab_Wo, mab_Wk, mab_bk,
                                          att_src, att_dst, gat_bias,
                                          pWh, pWl, wkh, ckh, vas, vad, bfin, csd);
    avec_kernel<<<N_NODES/4, 256, 0, stream>>>(node_embed, vas, vad, csd, node_ids, mask,
                                               a_s, a_d);
    assign_kernel<<<(N_NODES + 255)/256, 256, 0, stream>>>(mask, map, inv, cnt);
    pass1_kernel<<<(N_ITEMS + 255)/256, 256, 0, stream>>>(edge_idx, map, deg);
    scan_kernel<<<1, 256, 0, stream>>>(deg, rowp);
    pass2_kernel<<<(N_ITEMS + 255)/256, 256, 0, stream>>>(edge_idx, map, rowp, fill, colx);
    agg_kernel<<<NROWS/4, 256, 0, stream>>>(rowp, colx, inv, cnt, a_s, a_d, node_embed, acc);
    // X2 = acc @ Wc + (bc + gat_bias)  over compact rows  (MFMA split-bf16)
    mfma_lin_kernel<<<NROWS/64, 256, 0, stream>>>(acc, pWh, pWl, bfin, X2);
    gather_kernel<<<NROWS/4, 256, 0, stream>>>(node_ids, map, X2, X);

    for (int i = 0; i < 2; ++i) {
        int o = 2*i + 1;
        attn_partA_kernel<<<128, 256, 0, stream>>>(X, wkh + i*512, ckh + i*4, up, sp);
        attn_evenB_kernel<<<16, 512, 0, stream>>>(up, sp, qp + i*128,
                                                  mab_Wv + (2*i)*16384, mab_bv + (2*i)*128,
                                                  mab_Wo + (2*i)*16384, mab_bo + (2*i)*128,
                                                  mab_Wv + o*16384, mab_bv + o*128,
                                                  vpod);
        int mq = 1 + 2*i;     // packed slots: 1=Wq1, 2=Wo1, 3=Wq3, 4=Wo3
        int mo = 2 + 2*i;
        mfma_odd_kernel<<<NROWS/64, 256, 0, stream>>>(X,
                                                      pWh + mq*16384, pWl + mq*16384,
                                                      mab_bq + o*128, vpod,
                                                      pWh + mo*16384, pWl + mo*16384,
                                                      mab_bo + o*128, X);
    }
    attn_partA_kernel<<<128, 256, 0, stream>>>(X, wkh + 1024, ckh + 8, up, sp);
    attn_pmaB_kernel<<<16, 512, 0, stream>>>(up, sp, qp + 256,
                                             mab_Wq, mab_bq, mab_Wv, mab_bv, mab_Wo, mab_bo,
                                             dec_W, dec_b, protos, out);
}

// Round 9
// 259.886 us; speedup vs baseline: 1.1643x; 1.0740x over previous
//
#include <hip/hip_runtime.h>
#include <math.h>

#define N_NODES 50000
#define N_EDGES 600000
#define BATCH 16
#define SEQ 512
#define NROWS (BATCH*SEQ)   // 8192
#define N_ITEMS (N_EDGES + N_NODES)

// ---- workspace layout (float offsets) ----
#define OFF_X      0L
#define OFF_ACC    1048576L
#define OFF_X2     2097152L
#define OFF_WC     3245728L
#define OFF_BC     3262112L
#define OFF_QP     3262240L
#define OFF_WKH    3262624L
#define OFF_CKH    3264160L
#define OFF_VAS    3264176L
#define OFF_VAD    3264304L
#define OFF_BFIN   3264432L
#define OFF_CSD    3264560L
#define OFF_VPOD   3264564L
#define OFF_UP     3266612L          // 16*8*4*128 partial u
#define OFF_SP     3332148L          // 16*8*4 partial denom
#define OFF_PWH    3332660L          // 5 matrices x 16384 ushort (packed bf16 hi)
#define OFF_PWL    3373620L          // 5 matrices x 16384 ushort (packed bf16 lo)
// ---- zeroed-every-launch block (one memset) ----
#define OFF_MASK   3414580L
#define OFF_DEG    (OFF_MASK + 50000L)
#define OFF_FILL   (OFF_DEG + 8192L)
#define OFF_CNT    (OFF_FILL + 8192L)          // [cnt, pad, pad, pad]
#define ZERO_BYTES ((50000L + 8192L + 8192L + 4L) * 4L)
// ---- end zeroed block ----
#define OFF_MAP    (OFF_CNT + 4L)
#define OFF_INV    (OFF_MAP + 50000L)
#define OFF_ROWPTR (OFF_INV + 8192L)
#define OFF_COL    (OFF_ROWPTR + 8194L)

typedef __attribute__((ext_vector_type(8))) short bf16x8;
typedef __attribute__((ext_vector_type(4))) float f32x4;
#define MFMA16(a,b,c) __builtin_amdgcn_mfma_f32_16x16x32_bf16(a,b,c,0,0,0)

__device__ __forceinline__ unsigned short f2bf_rne(float f) {
    unsigned int u = __float_as_uint(f);
    unsigned int r = u + 0x7FFFu + ((u >> 16) & 1u);
    return (unsigned short)(r >> 16);
}
__device__ __forceinline__ float bf2f(unsigned short h) {
    return __uint_as_float(((unsigned int)h) << 16);
}
__device__ __forceinline__ float wave_allsum(float x) {
    #pragma unroll
    for (int off = 32; off > 0; off >>= 1) x += __shfl_xor(x, off);
    return x;
}

// ---------------- prep: Wc = lin_W @ gat_W, bc = lin_b @ gat_W, qp for mabs 0/2/4 ----------------
__global__ __launch_bounds__(256) void prep_kernel(
    const float* __restrict__ lin_W, const float* __restrict__ lin_b,
    const float* __restrict__ gat_W,
    const float* __restrict__ mab_Wq, const float* __restrict__ mab_bq,
    const float* __restrict__ isab_I, const float* __restrict__ pma_S,
    float* __restrict__ Wc, float* __restrict__ bc, float* __restrict__ qp)
{
    int t = blockIdx.x * 256 + threadIdx.x;
    if (t < 16384) {
        int i = t >> 7, j = t & 127;
        float s = 0.f;
        for (int k = 0; k < 128; ++k) s += lin_W[i*128 + k] * gat_W[k*128 + j];
        Wc[t] = s;
    } else if (t < 16512) {
        int j = t - 16384;
        float s = 0.f;
        for (int k = 0; k < 128; ++k) s += lin_b[k] * gat_W[k*128 + j];
        bc[j] = s;
    } else if (t < 16896) {
        int u = t - 16512;
        int m = u >> 7, c = u & 127;
        int mi = m * 2;   // mab index 0, 2, 4
        const float* vec = (m == 0) ? isab_I : (m == 1 ? isab_I + 128 : pma_S);
        float s = mab_bq[mi*128 + c];
        for (int k = 0; k < 128; ++k) s += vec[k] * mab_Wq[mi*16384 + k*128 + c];
        qp[u] = s;
    }
}

// ---------------- pack2: pack weights (MFMA B-frag hi/lo), wkh/ckh, vas/vad/bfin/csd, maskset ---
__global__ __launch_bounds__(256) void pack2_kernel(
    const float* __restrict__ Wc, const float* __restrict__ bc,
    const float* __restrict__ qp,
    const float* __restrict__ mab_Wq, const float* __restrict__ mab_Wo,
    const float* __restrict__ mab_Wk, const float* __restrict__ mab_bk,
    const float* __restrict__ att_src, const float* __restrict__ att_dst,
    const float* __restrict__ gat_bias, const int* __restrict__ node_ids,
    unsigned short* __restrict__ pWh, unsigned short* __restrict__ pWl,
    float* __restrict__ wkh, float* __restrict__ ckh,
    float* __restrict__ vas, float* __restrict__ vad,
    float* __restrict__ bfin, float* __restrict__ csd,
    int* __restrict__ mask)
{
    int b = blockIdx.x, t = threadIdx.x;
    if (b < 320) {
        int tid = b*256 + t;             // 5*16384
        int m = tid >> 14;
        int e = tid & 16383;
        int j = e & 7, l = (e>>3) & 63, ct = (e>>9) & 7, kc = e >> 12;
        int k = kc*32 + (l>>4)*8 + j;
        int c = ct*16 + (l & 15);
        const float* src;
        if (m == 0) src = Wc;
        else if (m == 1) src = mab_Wq + 1*16384;
        else if (m == 2) src = mab_Wo + 1*16384;
        else if (m == 3) src = mab_Wq + 3*16384;
        else src = mab_Wo + 3*16384;
        float v = src[k*128 + c];
        unsigned short h = f2bf_rne(v);
        pWh[tid] = h;
        pWl[tid] = f2bf_rne(v - bf2f(h));
    } else if (b == 320) {
        for (int it = 0; it < 6; ++it) {
            int u = it*256 + t;          // 1536 wkh entries
            int m = u >> 9, h = (u >> 7) & 3, j = u & 127;
            const float* Wk = mab_Wk + (2*m)*16384 + j*128 + h*32;
            const float* q  = qp + m*128 + h*32;
            float s = 0.f;
            #pragma unroll
            for (int d = 0; d < 32; ++d) s += Wk[d] * q[d];
            wkh[u] = s;
        }
        if (t < 12) {
            int m = t >> 2, h = t & 3;
            const float* bk = mab_bk + (2*m)*128 + h*32;
            const float* q  = qp + m*128 + h*32;
            float s = 0.f;
            #pragma unroll
            for (int d = 0; d < 32; ++d) s += bk[d] * q[d];
            ckh[t] = s;
        }
    } else if (b == 321) {
        if (t < 128) {
            float s = 0.f;
            for (int j = 0; j < 128; ++j) s += Wc[t*128 + j] * att_src[j];
            vas[t] = s;
            bfin[t] = bc[t] + gat_bias[t];
        } else {
            int k = t - 128;
            float s = 0.f;
            for (int j = 0; j < 128; ++j) s += Wc[k*128 + j] * att_dst[j];
            vad[k] = s;
        }
        if (t == 0) {
            float s = 0.f;
            for (int j = 0; j < 128; ++j) s += bc[j] * att_src[j];
            csd[0] = s;
        }
        if (t == 1) {
            float s = 0.f;
            for (int j = 0; j < 128; ++j) s += bc[j] * att_dst[j];
            csd[1] = s;
        }
    } else {
        int idx = (b - 322)*256 + t;     // 8192 maskset
        mask[node_ids[idx]] = 1;
    }
}

// ---------------- MFMA split-bf16 stage: acc += Xs_strip @ W  (3-term hi/lo split) --------------
__device__ __forceinline__ void mfma_stage(
    const float (*Xs)[132], int arow, int ao, int lane,
    const unsigned short* __restrict__ pWh, const unsigned short* __restrict__ pWl,
    f32x4 acc[8])
{
    #pragma unroll
    for (int kc = 0; kc < 4; ++kc) {
        float4 fa = *(const float4*)&Xs[arow][kc*32 + ao];
        float4 fb = *(const float4*)&Xs[arow][kc*32 + ao + 4];
        float f[8] = {fa.x, fa.y, fa.z, fa.w, fb.x, fb.y, fb.z, fb.w};
        bf16x8 ah, al;
        #pragma unroll
        for (int j = 0; j < 8; ++j) {
            unsigned short h = f2bf_rne(f[j]);
            ah[j] = (short)h;
            al[j] = (short)f2bf_rne(f[j] - bf2f(h));
        }
        #pragma unroll
        for (int ct = 0; ct < 8; ++ct) {
            int fo = ((kc*8 + ct)*64 + lane)*8;
            bf16x8 bh = *(const bf16x8*)(pWh + fo);
            bf16x8 bl = *(const bf16x8*)(pWl + fo);
            acc[ct] = MFMA16(ah, bh, acc[ct]);
            acc[ct] = MFMA16(ah, bl, acc[ct]);
            acc[ct] = MFMA16(al, bh, acc[ct]);
        }
    }
}

// ---------------- fused partA phase: logits + exp + partial u/denom from LDS rows ---------------
// all 256 threads; Xs holds the block's 64 rows; blk = b*8+chunk
__device__ __forceinline__ void partA_phase(
    const float (*Xs)[132], const float (*wks)[128], float (*esm)[64],
    const float* __restrict__ ckh, int blk, int t,
    float* __restrict__ up, float* __restrict__ sp)
{
    const float scale = 0.088388347648318447f;  // 1/sqrt(128)
    int wv = t >> 6, lane = t & 63;
    {
        float l = 0.f;
        for (int d4 = 0; d4 < 128; d4 += 4) {
            float4 xv = *(const float4*)&Xs[lane][d4];
            l += xv.x*wks[wv][d4] + xv.y*wks[wv][d4+1]
               + xv.z*wks[wv][d4+2] + xv.w*wks[wv][d4+3];
        }
        float e = __expf((l + ckh[wv]) * scale);
        esm[wv][lane] = e;
        float s = e;
        #pragma unroll
        for (int off = 32; off > 0; off >>= 1) s += __shfl_down(s, off);
        if (lane == 0) sp[blk*4 + wv] = s;
    }
    __syncthreads();
    {
        int hh = t >> 7, d = t & 127;
        float a0 = 0.f, a1 = 0.f;
        for (int k = 0; k < 64; ++k) {
            float xv = Xs[k][d];
            a0 += esm[2*hh][k] * xv;
            a1 += esm[2*hh + 1][k] * xv;
        }
        up[(blk*4 + 2*hh)*128 + d] = a0;
        up[(blk*4 + 2*hh + 1)*128 + d] = a1;
    }
}

// ---------------- MFMA linear: out = Xin(8192x128) @ W + b ----------------
__global__ __launch_bounds__(256) void mfma_lin_kernel(
    const float* __restrict__ Xin,
    const unsigned short* __restrict__ pWh, const unsigned short* __restrict__ pWl,
    const float* __restrict__ b1, float* __restrict__ out)
{
    __shared__ float Xs[64][132];
    int t = threadIdx.x;
    long row0 = (long)blockIdx.x * 64;
    #pragma unroll
    for (int i = 0; i < 32; ++i) {
        int idx = i*256 + t;
        int r = idx >> 7, k = idx & 127;
        Xs[r][k] = Xin[(row0 + r)*128 + k];
    }
    __syncthreads();
    int lane = t & 63, wv = t >> 6;
    int arow = wv*16 + (lane & 15), ao = (lane >> 4)*8;
    int crow0 = wv*16 + (lane >> 4)*4, ccol = lane & 15;
    f32x4 acc[8];
    #pragma unroll
    for (int ct = 0; ct < 8; ++ct) { acc[ct][0]=0.f; acc[ct][1]=0.f; acc[ct][2]=0.f; acc[ct][3]=0.f; }
    mfma_stage(Xs, arow, ao, lane, pWh, pWl, acc);
    #pragma unroll
    for (int ct = 0; ct < 8; ++ct) {
        int cc = ct*16 + ccol;
        float bb = b1[cc];
        #pragma unroll
        for (int i = 0; i < 4; ++i)
            out[(row0 + crow0 + i)*128 + cc] = acc[ct][i] + bb;
    }
}

// ---------------- gatherA: gather 64 rows + write X + fused partA (mab0) ------------------------
__global__ __launch_bounds__(256) void gatherA_kernel(
    const int* __restrict__ node_ids, const int* __restrict__ map,
    const float* __restrict__ X2, const float* __restrict__ wkh,
    const float* __restrict__ ckh,
    float* __restrict__ X, float* __restrict__ up, float* __restrict__ sp)
{
    __shared__ float Xs[64][132];
    __shared__ float wks[4][128];
    __shared__ float esm[4][64];
    __shared__ int cmap[64];
    int blk = blockIdx.x, t = threadIdx.x;
    long j0 = (long)blk * 64;
    if (t < 64) cmap[t] = map[node_ids[j0 + t]];
    #pragma unroll
    for (int i = 0; i < 2; ++i) { int u = i*256 + t; wks[u >> 7][u & 127] = wkh[u]; }
    __syncthreads();
    #pragma unroll
    for (int i = 0; i < 8; ++i) {
        int idx = i*256 + t;             // float4 index, 2048 total
        int r = idx >> 5, k4 = (idx & 31)*4;
        float4 v = *(const float4*)(X2 + (long)cmap[r]*128 + k4);
        *(float4*)&Xs[r][k4] = v;
        *(float4*)(X + (j0 + r)*128 + k4) = v;
    }
    __syncthreads();
    partA_phase(Xs, wks, esm, ckh, blk, t, up, sp);
}

// ---------------- odd-MAB fused: O1=X@Wq+bq+vpod; Xout=O1+relu(O1@Wo+bo); partA(next mab) -------
__global__ __launch_bounds__(256) void odd_fused_kernel(
    const float* __restrict__ Xin,
    const unsigned short* __restrict__ pQh, const unsigned short* __restrict__ pQl,
    const float* __restrict__ bq, const float* __restrict__ vpod,
    const unsigned short* __restrict__ pOh, const unsigned short* __restrict__ pOl,
    const float* __restrict__ bo,
    const float* __restrict__ wkh, const float* __restrict__ ckh,
    float* __restrict__ Xout, float* __restrict__ up, float* __restrict__ sp)
{
    __shared__ float Xs[64][132];
    __shared__ float wks[4][128];
    __shared__ float esm[4][64];
    int blk = blockIdx.x, t = threadIdx.x;
    long row0 = (long)blk * 64;
    #pragma unroll
    for (int i = 0; i < 32; ++i) {
        int idx = i*256 + t;
        int r = idx >> 7, k = idx & 127;
        Xs[r][k] = Xin[(row0 + r)*128 + k];
    }
    #pragma unroll
    for (int i = 0; i < 2; ++i) { int u = i*256 + t; wks[u >> 7][u & 127] = wkh[u]; }
    __syncthreads();
    int lane = t & 63, wv = t >> 6;
    int arow = wv*16 + (lane & 15), ao = (lane >> 4)*8;
    int crow0 = wv*16 + (lane >> 4)*4, ccol = lane & 15;
    int bidx = (int)(row0 >> 9);
    f32x4 acc[8];
    #pragma unroll
    for (int ct = 0; ct < 8; ++ct) { acc[ct][0]=0.f; acc[ct][1]=0.f; acc[ct][2]=0.f; acc[ct][3]=0.f; }
    mfma_stage(Xs, arow, ao, lane, pQh, pQl, acc);
    // stage-1 epilogue into own LDS strip (wave-local rows)
    #pragma unroll
    for (int ct = 0; ct < 8; ++ct) {
        int cc = ct*16 + ccol;
        float bb = bq[cc] + vpod[bidx*128 + cc];
        #pragma unroll
        for (int i = 0; i < 4; ++i) Xs[crow0 + i][cc] = acc[ct][i] + bb;
    }
    #pragma unroll
    for (int ct = 0; ct < 8; ++ct) { acc[ct][0]=0.f; acc[ct][1]=0.f; acc[ct][2]=0.f; acc[ct][3]=0.f; }
    mfma_stage(Xs, arow, ao, lane, pOh, pOl, acc);
    #pragma unroll
    for (int ct = 0; ct < 8; ++ct) {
        int cc = ct*16 + ccol;
        float bb = bo[cc];
        #pragma unroll
        for (int i = 0; i < 4; ++i) {
            float o1 = Xs[crow0 + i][cc];
            float v = o1 + fmaxf(acc[ct][i] + bb, 0.f);
            Xout[(row0 + crow0 + i)*128 + cc] = v;
            Xs[crow0 + i][cc] = v;       // wave-local overwrite with final value
        }
    }
    __syncthreads();
    partA_phase(Xs, wks, esm, ckh, blk, t, up, sp);
}

// ---------------- assign compact indices + inverse map (one atomic per BLOCK) -------------------
__global__ __launch_bounds__(256) void assign_kernel(
    const int* __restrict__ mask, int* __restrict__ map,
    int* __restrict__ inv, int* __restrict__ counter)
{
    __shared__ int wbase[4];
    int i = blockIdx.x*256 + threadIdx.x;
    bool act = (i < N_NODES) && mask[i];
    unsigned long long m = __ballot(act);
    int lane = threadIdx.x & 63;
    int w = threadIdx.x >> 6;
    if (lane == 0) wbase[w] = __popcll(m);
    __syncthreads();
    if (threadIdx.x == 0) {
        int tot = wbase[0] + wbase[1] + wbase[2] + wbase[3];
        int base = atomicAdd(counter, tot);
        int r = base;
        #pragma unroll
        for (int j = 0; j < 4; ++j) { int cj = wbase[j]; wbase[j] = r; r += cj; }
    }
    __syncthreads();
    if (i < N_NODES) {
        int c = -1;
        if (act) {
            c = wbase[w] + __popcll(m & ((1ull << lane) - 1ull));
            inv[c] = i;
        }
        map[i] = c;
    }
}

// ---------------- pass1: per-dest degree count (distributed atomics only) -----------------------
__global__ __launch_bounds__(256) void pass1_kernel(
    const int* __restrict__ edge_idx, const int* __restrict__ map,
    int* __restrict__ deg)
{
    int i = blockIdx.x*256 + threadIdx.x;
    if (i >= N_ITEMS) return;
    int dd = (i < N_EDGES) ? edge_idx[N_EDGES + i] : i - N_EDGES;
    int c = map[dd];
    if (c >= 0) atomicAdd(&deg[c], 1);
}

// ---------------- exclusive scan of deg[0..8191] -> rowptr (parallel prefix) --------------------
__global__ __launch_bounds__(256) void scan_kernel(const int* __restrict__ deg,
                                                   int* __restrict__ rowptr)
{
    __shared__ int wsum[4];
    int t = threadIdx.x;
    int base = t * 32;
    int s = 0;
    #pragma unroll
    for (int j = 0; j < 32; ++j) s += deg[base + j];
    int lane = t & 63, w = t >> 6;
    int v = s;
    #pragma unroll
    for (int off = 1; off < 64; off <<= 1) {
        int n = __shfl_up(v, off);
        if (lane >= off) v += n;
    }
    if (lane == 63) wsum[w] = v;
    __syncthreads();
    int wo = 0;
    for (int i = 0; i < 4; ++i) if (i < w) wo += wsum[i];
    int run = wo + v - s;                 // exclusive prefix of this 32-chunk
    #pragma unroll
    for (int j = 0; j < 32; ++j) { rowptr[base + j] = run; run += deg[base + j]; }
    if (t == 255) rowptr[8192] = run;
}

// ---------------- pass2: fill CSR column lists ----------------
__global__ __launch_bounds__(256) void pass2_kernel(
    const int* __restrict__ edge_idx, const int* __restrict__ map,
    const int* __restrict__ rowptr, int* __restrict__ fill,
    int* __restrict__ colx)
{
    int i = blockIdx.x*256 + threadIdx.x;
    if (i >= N_ITEMS) return;
    int s, dd;
    if (i < N_EDGES) { s = edge_idx[i]; dd = edge_idx[N_EDGES + i]; }
    else             { s = dd = i - N_EDGES; }
    int c = map[dd];
    if (c < 0) return;
    int pos = rowptr[c] + atomicAdd(&fill[c], 1);
    colx[pos] = s;
}

// ---------------- aggregate in embed space; a_s/a_d computed INLINE (avec deleted) --------------
__global__ __launch_bounds__(256) void agg_kernel(
    const int* __restrict__ rowptr, const int* __restrict__ colx,
    const int* __restrict__ inv, const int* __restrict__ cnt,
    const float* __restrict__ vas, const float* __restrict__ vad,
    const float* __restrict__ csd,
    const float* __restrict__ embed, float* __restrict__ acc)
{
    int c = blockIdx.x*4 + (threadIdx.x >> 6);
    int lane = threadIdx.x & 63;
    if (c >= *cnt) return;
    float va0 = vas[2*lane], va1 = vas[2*lane + 1];
    float vb0 = vad[2*lane], vb1 = vad[2*lane + 1];
    float csd0 = csd[0], csd1 = csd[1];
    int dd = inv[c];
    float2 wrow = *(const float2*)(embed + (long)dd*128 + lane*2);
    float ad = wave_allsum(wrow.x*vb0 + wrow.y*vb1) + csd1;
    int beg = rowptr[c], end = rowptr[c + 1];
    float s0 = 0.f, s1 = 0.f, den = 0.f;
    for (int j = beg; j < end; ++j) {
        int s = colx[j];
        float2 v = *(const float2*)(embed + (long)s*128 + lane*2);
        float as = wave_allsum(v.x*va0 + v.y*va1) + csd0;
        float e = as + ad;
        e = (e > 0.f) ? e : 0.2f * e;
        float ex = __expf(e);
        den += ex;
        s0 += ex * v.x;
        s1 += ex * v.y;
    }
    float inv_d = 1.f / den;
    float* o = acc + (long)c*128 + lane*2;
    o[0] = s0 * inv_d;
    o[1] = s1 * inv_d;
}

// ---------------- 128x128 matvec with 512 threads (4-way split-K + LDS reduce) -----------------
__device__ __forceinline__ float matvec_qs(
    const float* __restrict__ W, const float* xs, float (*red)[128], int t)
{
    int c = t & 127, q = t >> 7;
    float acc = 0.f;
    #pragma unroll
    for (int j = 0; j < 32; ++j) {
        int k = q*32 + j;
        acc += xs[k] * W[k*128 + c];
    }
    red[q][c] = acc;
    __syncthreads();
    float s = 0.f;
    if (t < 128) s = red[0][t] + red[1][t] + red[2][t] + red[3][t];
    __syncthreads();
    return s;
}

// ---------------- even MAB finish: warm-touch + reduce partials, O, H, vpod (grid 16) -----------
__global__ __launch_bounds__(512) void attn_evenB_kernel(
    const float* __restrict__ up, const float* __restrict__ sp,
    const float* __restrict__ qp,
    const float* __restrict__ Wv, const float* __restrict__ bv,
    const float* __restrict__ Wo, const float* __restrict__ bo,
    const float* __restrict__ Wv1, const float* __restrict__ bv1,
    float* __restrict__ vpod)
{
    __shared__ float u_sm[4][128];
    __shared__ float red[4][128];
    __shared__ float qs[128], Ovec[128], Hsm[128];
    int b = blockIdx.x, t = threadIdx.x;
    {   // parallel warm-touch
        float s = Wv[t*32] + Wo[t*32] + Wv1[t*32];
        asm volatile("" :: "v"(s));
    }
    if (t < 128) qs[t] = qp[t];
    {
        int h = t >> 7, d = t & 127;
        float s = 0.f, dn = 0.f;
        #pragma unroll
        for (int c = 0; c < 8; ++c) {
            s  += up[((b*8 + c)*4 + h)*128 + d];
            dn += sp[(b*8 + c)*4 + h];
        }
        u_sm[h][d] = s / dn;
    }
    __syncthreads();
    {
        int q4 = t >> 7, c = t & 127, h = c >> 5;
        float a = 0.f;
        #pragma unroll
        for (int j = 0; j < 32; ++j) {
            int k = q4*32 + j;
            a += u_sm[h][k] * Wv[k*128 + c];
        }
        red[q4][c] = a;
    }
    __syncthreads();
    if (t < 128) Ovec[t] = qs[t] + red[0][t] + red[1][t] + red[2][t] + red[3][t] + bv[t];
    __syncthreads();
    float mv = matvec_qs(Wo, Ovec, red, t);
    if (t < 128) Hsm[t] = Ovec[t] + fmaxf(mv + bo[t], 0.f);
    __syncthreads();
    float mv2 = matvec_qs(Wv1, Hsm, red, t);
    if (t < 128) vpod[b*128 + t] = mv2 + bv1[t];
}

// ---------------- PMA finish: warm-touch + reduce + SAB + SAB + dec + protos (grid 16) ----------
__global__ __launch_bounds__(512) void attn_pmaB_kernel(
    const float* __restrict__ up, const float* __restrict__ sp,
    const float* __restrict__ qp,
    const float* __restrict__ mab_Wq, const float* __restrict__ mab_bq,
    const float* __restrict__ mab_Wv, const float* __restrict__ mab_bv,
    const float* __restrict__ mab_Wo, const float* __restrict__ mab_bo,
    const float* __restrict__ dec_W, const float* __restrict__ dec_b,
    const float* __restrict__ protos, float* __restrict__ out)
{
    __shared__ float u_sm[4][128];
    __shared__ float red[4][128];
    __shared__ float qs[128], Ovec[128], S1[128], S2[128];
    int b = blockIdx.x, t = threadIdx.x;
    {   // warm-touch all 9 matrices of the chain
        const float* wq = mab_Wq + 5*16384;
        const float* wv = mab_Wv + 4*16384;
        const float* wo = mab_Wo + 4*16384;
        float s = 0.f;
        #pragma unroll
        for (int i = 0; i < 2; ++i) s += wq[(t + 512*i)*32];
        #pragma unroll
        for (int i = 0; i < 3; ++i) { s += wv[(t + 512*i)*32]; s += wo[(t + 512*i)*32]; }
        s += dec_W[t*32];
        asm volatile("" :: "v"(s));
    }
    if (t < 128) qs[t] = qp[t];
    {
        int h = t >> 7, d = t & 127;
        float s = 0.f, dn = 0.f;
        #pragma unroll
        for (int c = 0; c < 8; ++c) {
            s  += up[((b*8 + c)*4 + h)*128 + d];
            dn += sp[(b*8 + c)*4 + h];
        }
        u_sm[h][d] = s / dn;
    }
    __syncthreads();
    {
        int q4 = t >> 7, c = t & 127, h = c >> 5;
        float a = 0.f;
        #pragma unroll
        for (int j = 0; j < 32; ++j) {
            int k = q4*32 + j;
            a += u_sm[h][k] * (mab_Wv + 4*16384)[k*128 + c];
        }
        red[q4][c] = a;
    }
    __syncthreads();
    if (t < 128) Ovec[t] = qs[t] + red[0][t] + red[1][t] + red[2][t] + red[3][t]
                         + mab_bv[4*128 + t];
    __syncthreads();
    float mv = matvec_qs(mab_Wo + 4*16384, Ovec, red, t);
    if (t < 128) S1[t] = Ovec[t] + fmaxf(mv + mab_bo[4*128 + t], 0.f);
    __syncthreads();
    float q5 = matvec_qs(mab_Wq + 5*16384, S1, red, t);
    float v5 = matvec_qs(mab_Wv + 5*16384, S1, red, t);
    if (t < 128) S2[t] = q5 + mab_bq[5*128 + t] + v5 + mab_bv[5*128 + t];
    __syncthreads();
    float m5 = matvec_qs(mab_Wo + 5*16384, S2, red, t);
    if (t < 128) S1[t] = S2[t] + fmaxf(m5 + mab_bo[5*128 + t], 0.f);
    __syncthreads();
    float q6 = matvec_qs(mab_Wq + 6*16384, S1, red, t);
    float v6 = matvec_qs(mab_Wv + 6*16384, S1, red, t);
    if (t < 128) S2[t] = q6 + mab_bq[6*128 + t] + v6 + mab_bv[6*128 + t];
    __syncthreads();
    float m6 = matvec_qs(mab_Wo + 6*16384, S2, red, t);
    if (t < 128) S1[t] = S2[t] + fmaxf(m6 + mab_bo[6*128 + t], 0.f);
    __syncthreads();
    float y = matvec_qs(dec_W, S1, red, t);
    if (t < 128) out[b*768 + t] = y + dec_b[t];
    {
        int p = t >> 7, c = t & 127;
        out[b*768 + (1 + p)*128 + c] = protos[p*128 + c];
        if (t < 128) out[b*768 + 640 + t] = protos[512 + t];
    }
}

extern "C" void kernel_launch(void* const* d_in, const int* in_sizes, int n_in,
                              void* d_out, int out_size, void* d_ws, size_t ws_size,
                              hipStream_t stream)
{
    (void)in_sizes; (void)n_in; (void)out_size; (void)ws_size;
    const int*   node_ids  = (const int*)d_in[0];
    const int*   edge_idx  = (const int*)d_in[1];
    const float* node_embed= (const float*)d_in[3];
    const float* lin_W     = (const float*)d_in[4];
    const float* lin_b     = (const float*)d_in[5];
    const float* gat_W     = (const float*)d_in[6];
    const float* att_src   = (const float*)d_in[7];
    const float* att_dst   = (const float*)d_in[8];
    const float* gat_bias  = (const float*)d_in[9];
    const float* mab_Wq    = (const float*)d_in[10];
    const float* mab_bq    = (const float*)d_in[11];
    const float* mab_Wk    = (const float*)d_in[12];
    const float* mab_bk    = (const float*)d_in[13];
    const float* mab_Wv    = (const float*)d_in[14];
    const float* mab_bv    = (const float*)d_in[15];
    const float* mab_Wo    = (const float*)d_in[16];
    const float* mab_bo    = (const float*)d_in[17];
    const float* isab_I    = (const float*)d_in[18];
    const float* pma_S     = (const float*)d_in[19];
    const float* dec_W     = (const float*)d_in[20];
    const float* dec_b     = (const float*)d_in[21];
    const float* protos    = (const float*)d_in[22];

    float* ws    = (float*)d_ws;
    float* X     = ws + OFF_X;
    float* acc   = ws + OFF_ACC;
    float* X2    = ws + OFF_X2;
    float* Wc    = ws + OFF_WC;
    float* bc    = ws + OFF_BC;
    float* qp    = ws + OFF_QP;
    float* wkh   = ws + OFF_WKH;
    float* ckh   = ws + OFF_CKH;
    float* vas   = ws + OFF_VAS;
    float* vad   = ws + OFF_VAD;
    float* bfin  = ws + OFF_BFIN;
    float* csd   = ws + OFF_CSD;
    float* vpod  = ws + OFF_VPOD;
    float* up    = ws + OFF_UP;
    float* sp    = ws + OFF_SP;
    unsigned short* pWh = (unsigned short*)(ws + OFF_PWH);
    unsigned short* pWl = (unsigned short*)(ws + OFF_PWL);
    int*   mask  = (int*)(ws + OFF_MASK);
    int*   deg   = (int*)(ws + OFF_DEG);
    int*   fill  = (int*)(ws + OFF_FILL);
    int*   cnt   = (int*)(ws + OFF_CNT);
    int*   map   = (int*)(ws + OFF_MAP);
    int*   inv   = (int*)(ws + OFF_INV);
    int*   rowp  = (int*)(ws + OFF_ROWPTR);
    int*   colx  = (int*)(ws + OFF_COL);
    float* out   = (float*)d_out;

    hipMemsetAsync(ws + OFF_MASK, 0, ZERO_BYTES, stream);

    prep_kernel<<<66, 256, 0, stream>>>(lin_W, lin_b, gat_W, mab_Wq, mab_bq, isab_I, pma_S,
                                        Wc, bc, qp);
    pack2_kernel<<<354, 256, 0, stream>>>(Wc, bc, qp, mab_Wq, mab_Wo, mab_Wk, mab_bk,
                                          att_src, att_dst, gat_bias, node_ids,
                                          pWh, pWl, wkh, ckh, vas, vad, bfin, csd, mask);
    assign_kernel<<<(N_NODES + 255)/256, 256, 0, stream>>>(mask, map, inv, cnt);
    pass1_kernel<<<(N_ITEMS + 255)/256, 256, 0, stream>>>(edge_idx, map, deg);
    scan_kernel<<<1, 256, 0, stream>>>(deg, rowp);
    pass2_kernel<<<(N_ITEMS + 255)/256, 256, 0, stream>>>(edge_idx, map, rowp, fill, colx);
    agg_kernel<<<NROWS/4, 256, 0, stream>>>(rowp, colx, inv, cnt, vas, vad, csd,
                                            node_embed, acc);
    mfma_lin_kernel<<<NROWS/64, 256, 0, stream>>>(acc, pWh, pWl, bfin, X2);
    gatherA_kernel<<<NROWS/64, 256, 0, stream>>>(node_ids, map, X2, wkh, ckh, X, up, sp);

    for (int i = 0; i < 2; ++i) {
        int o = 2*i + 1;
        attn_evenB_kernel<<<16, 512, 0, stream>>>(up, sp, qp + i*128,
                                                  mab_Wv + (2*i)*16384, mab_bv + (2*i)*128,
                                                  mab_Wo + (2*i)*16384, mab_bo + (2*i)*128,
                                                  mab_Wv + o*16384, mab_bv + o*128,
                                                  vpod);
        int mq = 1 + 2*i;     // packed slots: 1=Wq1, 2=Wo1, 3=Wq3, 4=Wo3
        int mo = 2 + 2*i;
        odd_fused_kernel<<<NROWS/64, 256, 0, stream>>>(X,
                                                       pWh + mq*16384, pWl + mq*16384,
                                                       mab_bq + o*128, vpod,
                                                       pWh + mo*16384, pWl + mo*16384,
                                                       mab_bo + o*128,
                                                       wkh + (i + 1)*512, ckh + (i + 1)*4,
                                                       X, up, sp);
    }
    attn_pmaB_kernel<<<16, 512, 0, stream>>>(up, sp, qp + 256,
                                             mab_Wq, mab_bq, mab_Wv, mab_bv, mab_Wo, mab_bo,
                                             dec_W, dec_b, protos, out);
}

// Round 10
// 258.150 us; speedup vs baseline: 1.1721x; 1.0067x over previous
//
#include <hip/hip_runtime.h>
#include <math.h>

#define N_NODES 50000
#define N_EDGES 600000
#define BATCH 16
#define SEQ 512
#define NROWS (BATCH*SEQ)   // 8192
#define N_ITEMS (N_EDGES + N_NODES)

// ---- workspace layout (float offsets) ----
#define OFF_X      0L
#define OFF_ACC    1048576L
#define OFF_X2     2097152L
#define OFF_QP     3145728L
#define OFF_WKH    3146112L
#define OFF_CKH    3147648L
#define OFF_VAS    3147664L
#define OFF_VAD    3147792L
#define OFF_BFIN   3147920L
#define OFF_CSD    3148048L
#define OFF_UPA    3148052L
#define OFF_SPA    3213588L
#define OFF_UPB    3214100L
#define OFF_SPB    3279636L
#define OFF_PWH    3280148L          // 5 matrices x 16384 ushort (packed bf16 hi)
#define OFF_PWL    3321108L
// ---- zeroed-every-launch block (one memset): mask + cnt ----
#define OFF_MASK   3362068L
#define OFF_CNT    (OFF_MASK + 50000L)
#define ZERO_BYTES ((50000L + 4L) * 4L)
// ---- end zeroed block (deg/fill zeroed inside assign_kernel) ----
#define OFF_DEG    (OFF_CNT + 4L)
#define OFF_FILL   (OFF_DEG + 8192L)
#define OFF_MAP    (OFF_FILL + 8192L)
#define OFF_INV    (OFF_MAP + 50000L)
#define OFF_ROWPTR (OFF_INV + 8192L)
#define OFF_COL    (OFF_ROWPTR + 8194L)

typedef __attribute__((ext_vector_type(8))) short bf16x8;
typedef __attribute__((ext_vector_type(4))) float f32x4;
#define MFMA16(a,b,c) __builtin_amdgcn_mfma_f32_16x16x32_bf16(a,b,c,0,0,0)

__device__ __forceinline__ unsigned short f2bf_rne(float f) {
    unsigned int u = __float_as_uint(f);
    unsigned int r = u + 0x7FFFu + ((u >> 16) & 1u);
    return (unsigned short)(r >> 16);
}
__device__ __forceinline__ float bf2f(unsigned short h) {
    return __uint_as_float(((unsigned int)h) << 16);
}
__device__ __forceinline__ float wave_allsum(float x) {
    #pragma unroll
    for (int off = 32; off > 0; off >>= 1) x += __shfl_xor(x, off);
    return x;
}

// ---------------- prep_all: pack weights (Wc inline), qp/wkh/ckh, vas/vad/bfin/csd, maskset -----
__global__ __launch_bounds__(256) void prep_all_kernel(
    const float* __restrict__ lin_W, const float* __restrict__ lin_b,
    const float* __restrict__ gat_W,
    const float* __restrict__ mab_Wq, const float* __restrict__ mab_bq,
    const float* __restrict__ mab_Wk, const float* __restrict__ mab_bk,
    const float* __restrict__ mab_Wo,
    const float* __restrict__ att_src, const float* __restrict__ att_dst,
    const float* __restrict__ gat_bias,
    const float* __restrict__ isab_I, const float* __restrict__ pma_S,
    const int* __restrict__ node_ids,
    unsigned short* __restrict__ pWh, unsigned short* __restrict__ pWl,
    float* __restrict__ qp, float* __restrict__ wkh, float* __restrict__ ckh,
    float* __restrict__ vas, float* __restrict__ vad,
    float* __restrict__ bfin, float* __restrict__ csd,
    int* __restrict__ mask)
{
    int b = blockIdx.x, t = threadIdx.x;
    if (b < 320) {
        int tid = b*256 + t;             // 5*16384
        int m = tid >> 14;
        int e = tid & 16383;
        int j = e & 7, l = (e>>3) & 63, ct = (e>>9) & 7, kc = e >> 12;
        int k = kc*32 + (l>>4)*8 + j;
        int c = ct*16 + (l & 15);
        float v;
        if (m == 0) {                    // Wc[k][c] = lin_W[k,:] . gat_W[:,c] inline
            float s = 0.f;
            for (int r = 0; r < 128; ++r) s += lin_W[k*128 + r] * gat_W[r*128 + c];
            v = s;
        } else {
            const float* src = (m == 1) ? mab_Wq + 1*16384
                             : (m == 2) ? mab_Wo + 1*16384
                             : (m == 3) ? mab_Wq + 3*16384
                             :            mab_Wo + 3*16384;
            v = src[k*128 + c];
        }
        unsigned short h = f2bf_rne(v);
        pWh[tid] = h;
        pWl[tid] = f2bf_rne(v - bf2f(h));
    } else if (b == 320) {
        __shared__ float qps[384];
        for (int u = t; u < 384; u += 256) {
            int m = u >> 7, c = u & 127;
            int mi = m * 2;              // mab 0, 2, 4
            const float* vec = (m == 0) ? isab_I : (m == 1 ? isab_I + 128 : pma_S);
            float s = mab_bq[mi*128 + c];
            for (int k = 0; k < 128; ++k) s += vec[k] * mab_Wq[mi*16384 + k*128 + c];
            qps[u] = s;
            qp[u] = s;
        }
        __syncthreads();
        for (int it = 0; it < 6; ++it) {
            int u = it*256 + t;          // 1536 wkh entries
            int m = u >> 9, h = (u >> 7) & 3, j = u & 127;
            const float* Wk = mab_Wk + (2*m)*16384 + j*128 + h*32;
            const float* q  = qps + m*128 + h*32;
            float s = 0.f;
            #pragma unroll
            for (int d = 0; d < 32; ++d) s += Wk[d] * q[d];
            wkh[u] = s;
        }
        if (t < 12) {
            int m = t >> 2, h = t & 3;
            const float* bk = mab_bk + (2*m)*128 + h*32;
            const float* q  = qps + m*128 + h*32;
            float s = 0.f;
            #pragma unroll
            for (int d = 0; d < 32; ++d) s += bk[d] * q[d];
            ckh[t] = s;
        }
    } else if (b == 321) {
        __shared__ float gs[128], gd[128], lb[128];
        if (t < 128) {
            float s = 0.f, d2 = 0.f;
            for (int j = 0; j < 128; ++j) {
                float g = gat_W[t*128 + j];
                s  += g * att_src[j];
                d2 += g * att_dst[j];
            }
            gs[t] = s; gd[t] = d2; lb[t] = lin_b[t];
        }
        __syncthreads();
        if (t < 128) {
            float s = 0.f, d2 = 0.f, bcv = 0.f;
            for (int k = 0; k < 128; ++k) {
                float lw = lin_W[t*128 + k];
                s  += lw * gs[k];
                d2 += lw * gd[k];
                bcv += lb[k] * gat_W[k*128 + t];
            }
            vas[t] = s;                  // Wc[t,:] . att_src
            vad[t] = d2;
            bfin[t] = bcv + gat_bias[t]; // bc + gat_bias
        }
        if (t == 0) { float s = 0.f; for (int k = 0; k < 128; ++k) s += lb[k]*gs[k]; csd[0] = s; }
        if (t == 1) { float s = 0.f; for (int k = 0; k < 128; ++k) s += lb[k]*gd[k]; csd[1] = s; }
    } else {
        int idx = (b - 322)*256 + t;     // 8192 maskset
        mask[node_ids[idx]] = 1;
    }
}

// ---------------- MFMA split-bf16 stage: acc += Xs_strip @ W  (3-term hi/lo split) --------------
__device__ __forceinline__ void mfma_stage(
    const float (*Xs)[132], int arow, int ao, int lane,
    const unsigned short* __restrict__ pWh, const unsigned short* __restrict__ pWl,
    f32x4 acc[8])
{
    #pragma unroll
    for (int kc = 0; kc < 4; ++kc) {
        float4 fa = *(const float4*)&Xs[arow][kc*32 + ao];
        float4 fb = *(const float4*)&Xs[arow][kc*32 + ao + 4];
        float f[8] = {fa.x, fa.y, fa.z, fa.w, fb.x, fb.y, fb.z, fb.w};
        bf16x8 ah, al;
        #pragma unroll
        for (int j = 0; j < 8; ++j) {
            unsigned short h = f2bf_rne(f[j]);
            ah[j] = (short)h;
            al[j] = (short)f2bf_rne(f[j] - bf2f(h));
        }
        #pragma unroll
        for (int ct = 0; ct < 8; ++ct) {
            int fo = ((kc*8 + ct)*64 + lane)*8;
            bf16x8 bh = *(const bf16x8*)(pWh + fo);
            bf16x8 bl = *(const bf16x8*)(pWl + fo);
            acc[ct] = MFMA16(ah, bh, acc[ct]);
            acc[ct] = MFMA16(ah, bl, acc[ct]);
            acc[ct] = MFMA16(al, bh, acc[ct]);
        }
    }
}

// ---------------- fused partA phase: logits + exp + partial u/denom from LDS rows ---------------
__device__ __forceinline__ void partA_phase(
    const float (*Xs)[132], const float (*wks)[128], float (*esm)[64],
    const float* __restrict__ ckh, int blk, int t,
    float* __restrict__ up, float* __restrict__ sp)
{
    const float scale = 0.088388347648318447f;  // 1/sqrt(128)
    int wv = t >> 6, lane = t & 63;
    {
        float l = 0.f;
        for (int d4 = 0; d4 < 128; d4 += 4) {
            float4 xv = *(const float4*)&Xs[lane][d4];
            l += xv.x*wks[wv][d4] + xv.y*wks[wv][d4+1]
               + xv.z*wks[wv][d4+2] + xv.w*wks[wv][d4+3];
        }
        float e = __expf((l + ckh[wv]) * scale);
        esm[wv][lane] = e;
        float s = e;
        #pragma unroll
        for (int off = 32; off > 0; off >>= 1) s += __shfl_down(s, off);
        if (lane == 0) sp[blk*4 + wv] = s;
    }
    __syncthreads();
    {
        int hh = t >> 7, d = t & 127;
        float a0 = 0.f, a1 = 0.f;
        for (int k = 0; k < 64; ++k) {
            float xv = Xs[k][d];
            a0 += esm[2*hh][k] * xv;
            a1 += esm[2*hh + 1][k] * xv;
        }
        up[(blk*4 + 2*hh)*128 + d] = a0;
        up[(blk*4 + 2*hh + 1)*128 + d] = a1;
    }
}

// ---------------- 128x128 matvec with 256 threads (2-way split-K + LDS reduce) ------------------
__device__ __forceinline__ float matvec256(
    const float* __restrict__ W, const float* xs, float (*red)[128], int t)
{
    int c = t & 127, q = t >> 7;
    float a = 0.f;
    #pragma unroll
    for (int j = 0; j < 64; ++j) {
        int k = q*64 + j;
        a += xs[k] * W[k*128 + c];
    }
    red[q][c] = a;
    __syncthreads();
    float s = 0.f;
    if (t < 128) s = red[0][t] + red[1][t];
    __syncthreads();
    return s;
}

// ---------------- MFMA linear: out = Xin(8192x128) @ W + b ----------------
__global__ __launch_bounds__(256) void mfma_lin_kernel(
    const float* __restrict__ Xin,
    const unsigned short* __restrict__ pWh, const unsigned short* __restrict__ pWl,
    const float* __restrict__ b1, float* __restrict__ out)
{
    __shared__ float Xs[64][132];
    int t = threadIdx.x;
    long row0 = (long)blockIdx.x * 64;
    #pragma unroll
    for (int i = 0; i < 8; ++i) {
        int idx = i*256 + t;
        int r = idx >> 5, k4 = (idx & 31)*4;
        *(float4*)&Xs[r][k4] = *(const float4*)(Xin + (row0 + r)*128 + k4);
    }
    __syncthreads();
    int lane = t & 63, wv = t >> 6;
    int arow = wv*16 + (lane & 15), ao = (lane >> 4)*8;
    int crow0 = wv*16 + (lane >> 4)*4, ccol = lane & 15;
    f32x4 acc[8];
    #pragma unroll
    for (int ct = 0; ct < 8; ++ct) { acc[ct][0]=0.f; acc[ct][1]=0.f; acc[ct][2]=0.f; acc[ct][3]=0.f; }
    mfma_stage(Xs, arow, ao, lane, pWh, pWl, acc);
    #pragma unroll
    for (int ct = 0; ct < 8; ++ct) {
        int cc = ct*16 + ccol;
        float bb = b1[cc];
        #pragma unroll
        for (int i = 0; i < 4; ++i)
            out[(row0 + crow0 + i)*128 + cc] = acc[ct][i] + bb;
    }
}

// ---------------- gatherA: gather 64 rows + write X + fused partA (mab0) ------------------------
__global__ __launch_bounds__(256) void gatherA_kernel(
    const int* __restrict__ node_ids, const int* __restrict__ map,
    const float* __restrict__ X2, const float* __restrict__ wkh,
    const float* __restrict__ ckh,
    float* __restrict__ X, float* __restrict__ up, float* __restrict__ sp)
{
    __shared__ float Xs[64][132];
    __shared__ float wks[4][128];
    __shared__ float esm[4][64];
    __shared__ int cmap[64];
    int blk = blockIdx.x, t = threadIdx.x;
    long j0 = (long)blk * 64;
    if (t < 64) cmap[t] = map[node_ids[j0 + t]];
    #pragma unroll
    for (int i = 0; i < 2; ++i) { int u = i*256 + t; wks[u >> 7][u & 127] = wkh[u]; }
    __syncthreads();
    #pragma unroll
    for (int i = 0; i < 8; ++i) {
        int idx = i*256 + t;             // float4 index, 2048 total
        int r = idx >> 5, k4 = (idx & 31)*4;
        float4 v = *(const float4*)(X2 + (long)cmap[r]*128 + k4);
        *(float4*)&Xs[r][k4] = v;
        *(float4*)(X + (j0 + r)*128 + k4) = v;
    }
    __syncthreads();
    partA_phase(Xs, wks, esm, ckh, blk, t, up, sp);
}

// ---------------- odd-MAB fused: inline evenB (redundant per block) + MFMA odd + partA ----------
__global__ __launch_bounds__(256) void odd_fused_kernel(
    const float* __restrict__ Xin,
    const float* __restrict__ upIn, const float* __restrict__ spIn,
    const float* __restrict__ qpe,
    const float* __restrict__ Wv_e, const float* __restrict__ bv_e,
    const float* __restrict__ Wo_e, const float* __restrict__ bo_e,
    const unsigned short* __restrict__ pQh, const unsigned short* __restrict__ pQl,
    const float* __restrict__ bq,
    const unsigned short* __restrict__ pOh, const unsigned short* __restrict__ pOl,
    const float* __restrict__ bo,
    const float* __restrict__ Wv1, const float* __restrict__ bv1,
    const float* __restrict__ wkh, const float* __restrict__ ckh,
    float* __restrict__ Xout, float* __restrict__ upOut, float* __restrict__ spOut)
{
    __shared__ float Xs[64][132];
    __shared__ float wks[4][128];
    __shared__ float esm[4][64];
    __shared__ float u_sm[4][128];
    __shared__ float red[2][128];
    __shared__ float qs[128], Ovec[128], Hsm[128], vp[128];
    int blk = blockIdx.x, t = threadIdx.x;
    long row0 = (long)blk * 64;
    int bidx = (int)(row0 >> 9);
    // stage X (float4) and wks — consumed after the evenB phase's barriers
    #pragma unroll
    for (int i = 0; i < 8; ++i) {
        int idx = i*256 + t;
        int r = idx >> 5, k4 = (idx & 31)*4;
        *(float4*)&Xs[r][k4] = *(const float4*)(Xin + (row0 + r)*128 + k4);
    }
    #pragma unroll
    for (int i = 0; i < 2; ++i) { int u = i*256 + t; wks[u >> 7][u & 127] = wkh[u]; }
    if (t < 128) qs[t] = qpe[t];
    // ---- inline evenB for this block's batch (redundant across the 8 blocks of a batch) ----
    {
        int d = t & 127;
        #pragma unroll
        for (int hh = 0; hh < 2; ++hh) {
            int h = hh*2 + (t >> 7);
            float s = 0.f, dn = 0.f;
            #pragma unroll
            for (int c = 0; c < 8; ++c) {
                s  += upIn[((bidx*8 + c)*4 + h)*128 + d];
                dn += spIn[(bidx*8 + c)*4 + h];
            }
            u_sm[h][d] = s / dn;
        }
    }
    __syncthreads();
    {   // O[c] = qs[c] + u_{c>>5} @ Wv_e[:,c] + bv_e[c]
        int q = t >> 7, c = t & 127, h = c >> 5;
        float a = 0.f;
        #pragma unroll
        for (int j = 0; j < 64; ++j) {
            int k = q*64 + j;
            a += u_sm[h][k] * Wv_e[k*128 + c];
        }
        red[q][c] = a;
    }
    __syncthreads();
    if (t < 128) Ovec[t] = qs[t] + red[0][t] + red[1][t] + bv_e[t];
    __syncthreads();
    float mv = matvec256(Wo_e, Ovec, red, t);
    if (t < 128) Hsm[t] = Ovec[t] + fmaxf(mv + bo_e[t], 0.f);
    __syncthreads();
    float mv2 = matvec256(Wv1, Hsm, red, t);
    if (t < 128) vp[t] = mv2 + bv1[t];
    __syncthreads();
    // ---- odd MAB: O1 = X@Wq + bq + vp; Xout = O1 + relu(O1@Wo + bo) ----
    int lane = t & 63, wv = t >> 6;
    int arow = wv*16 + (lane & 15), ao = (lane >> 4)*8;
    int crow0 = wv*16 + (lane >> 4)*4, ccol = lane & 15;
    f32x4 acc[8];
    #pragma unroll
    for (int ct = 0; ct < 8; ++ct) { acc[ct][0]=0.f; acc[ct][1]=0.f; acc[ct][2]=0.f; acc[ct][3]=0.f; }
    mfma_stage(Xs, arow, ao, lane, pQh, pQl, acc);
    #pragma unroll
    for (int ct = 0; ct < 8; ++ct) {
        int cc = ct*16 + ccol;
        float bb = bq[cc] + vp[cc];
        #pragma unroll
        for (int i = 0; i < 4; ++i) Xs[crow0 + i][cc] = acc[ct][i] + bb;
    }
    #pragma unroll
    for (int ct = 0; ct < 8; ++ct) { acc[ct][0]=0.f; acc[ct][1]=0.f; acc[ct][2]=0.f; acc[ct][3]=0.f; }
    mfma_stage(Xs, arow, ao, lane, pOh, pOl, acc);
    #pragma unroll
    for (int ct = 0; ct < 8; ++ct) {
        int cc = ct*16 + ccol;
        float bb = bo[cc];
        #pragma unroll
        for (int i = 0; i < 4; ++i) {
            float o1 = Xs[crow0 + i][cc];
            float v = o1 + fmaxf(acc[ct][i] + bb, 0.f);
            Xout[(row0 + crow0 + i)*128 + cc] = v;
            Xs[crow0 + i][cc] = v;       // wave-local overwrite with final value
        }
    }
    __syncthreads();
    partA_phase(Xs, wks, esm, ckh, blk, t, upOut, spOut);
}

// ---------------- assign compact indices + inverse map + zero deg/fill --------------------------
__global__ __launch_bounds__(256) void assign_kernel(
    const int* __restrict__ mask, int* __restrict__ map,
    int* __restrict__ inv, int* __restrict__ counter,
    int* __restrict__ deg, int* __restrict__ fill)
{
    __shared__ int wbase[4];
    int i = blockIdx.x*256 + threadIdx.x;
    if (i < 8192) { deg[i] = 0; fill[i] = 0; }
    bool act = (i < N_NODES) && mask[i];
    unsigned long long m = __ballot(act);
    int lane = threadIdx.x & 63;
    int w = threadIdx.x >> 6;
    if (lane == 0) wbase[w] = __popcll(m);
    __syncthreads();
    if (threadIdx.x == 0) {
        int tot = wbase[0] + wbase[1] + wbase[2] + wbase[3];
        int base = atomicAdd(counter, tot);
        int r = base;
        #pragma unroll
        for (int j = 0; j < 4; ++j) { int cj = wbase[j]; wbase[j] = r; r += cj; }
    }
    __syncthreads();
    if (i < N_NODES) {
        int c = -1;
        if (act) {
            c = wbase[w] + __popcll(m & ((1ull << lane) - 1ull));
            inv[c] = i;
        }
        map[i] = c;
    }
}

// ---------------- pass1: per-dest degree count (distributed atomics only) -----------------------
__global__ __launch_bounds__(256) void pass1_kernel(
    const int* __restrict__ edge_idx, const int* __restrict__ map,
    int* __restrict__ deg)
{
    int i = blockIdx.x*256 + threadIdx.x;
    if (i >= N_ITEMS) return;
    int dd = (i < N_EDGES) ? edge_idx[N_EDGES + i] : i - N_EDGES;
    int c = map[dd];
    if (c >= 0) atomicAdd(&deg[c], 1);
}

// ---------------- exclusive scan of deg[0..8191] -> rowptr (parallel prefix) --------------------
__global__ __launch_bounds__(256) void scan_kernel(const int* __restrict__ deg,
                                                   int* __restrict__ rowptr)
{
    __shared__ int wsum[4];
    int t = threadIdx.x;
    int base = t * 32;
    int s = 0;
    #pragma unroll
    for (int j = 0; j < 32; ++j) s += deg[base + j];
    int lane = t & 63, w = t >> 6;
    int v = s;
    #pragma unroll
    for (int off = 1; off < 64; off <<= 1) {
        int n = __shfl_up(v, off);
        if (lane >= off) v += n;
    }
    if (lane == 63) wsum[w] = v;
    __syncthreads();
    int wo = 0;
    for (int i = 0; i < 4; ++i) if (i < w) wo += wsum[i];
    int run = wo + v - s;                 // exclusive prefix of this 32-chunk
    #pragma unroll
    for (int j = 0; j < 32; ++j) { rowptr[base + j] = run; run += deg[base + j]; }
    if (t == 255) rowptr[8192] = run;
}

// ---------------- pass2: fill CSR column lists ----------------
__global__ __launch_bounds__(256) void pass2_kernel(
    const int* __restrict__ edge_idx, const int* __restrict__ map,
    const int* __restrict__ rowptr, int* __restrict__ fill,
    int* __restrict__ colx)
{
    int i = blockIdx.x*256 + threadIdx.x;
    if (i >= N_ITEMS) return;
    int s, dd;
    if (i < N_EDGES) { s = edge_idx[i]; dd = edge_idx[N_EDGES + i]; }
    else             { s = dd = i - N_EDGES; }
    int c = map[dd];
    if (c < 0) return;
    int pos = rowptr[c] + atomicAdd(&fill[c], 1);
    colx[pos] = s;
}

// ---------------- aggregate in embed space; a_s/a_d computed inline -----------------------------
__global__ __launch_bounds__(256) void agg_kernel(
    const int* __restrict__ rowptr, const int* __restrict__ colx,
    const int* __restrict__ inv, const int* __restrict__ cnt,
    const float* __restrict__ vas, const float* __restrict__ vad,
    const float* __restrict__ csd,
    const float* __restrict__ embed, float* __restrict__ acc)
{
    int c = blockIdx.x*4 + (threadIdx.x >> 6);
    int lane = threadIdx.x & 63;
    if (c >= *cnt) return;
    float va0 = vas[2*lane], va1 = vas[2*lane + 1];
    float vb0 = vad[2*lane], vb1 = vad[2*lane + 1];
    float csd0 = csd[0], csd1 = csd[1];
    int dd = inv[c];
    float2 wrow = *(const float2*)(embed + (long)dd*128 + lane*2);
    float ad = wave_allsum(wrow.x*vb0 + wrow.y*vb1) + csd1;
    int beg = rowptr[c], end = rowptr[c + 1];
    float s0 = 0.f, s1 = 0.f, den = 0.f;
    for (int j = beg; j < end; ++j) {
        int s = colx[j];
        float2 v = *(const float2*)(embed + (long)s*128 + lane*2);
        float as = wave_allsum(v.x*va0 + v.y*va1) + csd0;
        float e = as + ad;
        e = (e > 0.f) ? e : 0.2f * e;
        float ex = __expf(e);
        den += ex;
        s0 += ex * v.x;
        s1 += ex * v.y;
    }
    float inv_d = 1.f / den;
    float* o = acc + (long)c*128 + lane*2;
    o[0] = s0 * inv_d;
    o[1] = s1 * inv_d;
}

// ---------------- 128x128 matvec with 512 threads (4-way split-K + LDS reduce) -----------------
__device__ __forceinline__ float matvec_qs(
    const float* __restrict__ W, const float* xs, float (*red)[128], int t)
{
    int c = t & 127, q = t >> 7;
    float acc = 0.f;
    #pragma unroll
    for (int j = 0; j < 32; ++j) {
        int k = q*32 + j;
        acc += xs[k] * W[k*128 + c];
    }
    red[q][c] = acc;
    __syncthreads();
    float s = 0.f;
    if (t < 128) s = red[0][t] + red[1][t] + red[2][t] + red[3][t];
    __syncthreads();
    return s;
}

// ---------------- PMA finish: warm-touch + reduce + SAB + SAB + dec + protos (grid 16) ----------
__global__ __launch_bounds__(512) void attn_pmaB_kernel(
    const float* __restrict__ up, const float* __restrict__ sp,
    const float* __restrict__ qp,
    const float* __restrict__ mab_Wq, const float* __restrict__ mab_bq,
    const float* __restrict__ mab_Wv, const float* __restrict__ mab_bv,
    const float* __restrict__ mab_Wo, const float* __restrict__ mab_bo,
    const float* __restrict__ dec_W, const float* __restrict__ dec_b,
    const float* __restrict__ protos, float* __restrict__ out)
{
    __shared__ float u_sm[4][128];
    __shared__ float red[4][128];
    __shared__ float qs[128], Ovec[128], S1[128], S2[128];
    int b = blockIdx.x, t = threadIdx.x;
    {   // warm-touch all 9 matrices of the chain
        const float* wq = mab_Wq + 5*16384;
        const float* wv = mab_Wv + 4*16384;
        const float* wo = mab_Wo + 4*16384;
        float s = 0.f;
        #pragma unroll
        for (int i = 0; i < 2; ++i) s += wq[(t + 512*i)*32];
        #pragma unroll
        for (int i = 0; i < 3; ++i) { s += wv[(t + 512*i)*32]; s += wo[(t + 512*i)*32]; }
        s += dec_W[t*32];
        asm volatile("" :: "v"(s));
    }
    if (t < 128) qs[t] = qp[t];
    {
        int h = t >> 7, d = t & 127;
        float s = 0.f, dn = 0.f;
        #pragma unroll
        for (int c = 0; c < 8; ++c) {
            s  += up[((b*8 + c)*4 + h)*128 + d];
            dn += sp[(b*8 + c)*4 + h];
        }
        u_sm[h][d] = s / dn;
    }
    __syncthreads();
    {
        int q4 = t >> 7, c = t & 127, h = c >> 5;
        float a = 0.f;
        #pragma unroll
        for (int j = 0; j < 32; ++j) {
            int k = q4*32 + j;
            a += u_sm[h][k] * (mab_Wv + 4*16384)[k*128 + c];
        }
        red[q4][c] = a;
    }
    __syncthreads();
    if (t < 128) Ovec[t] = qs[t] + red[0][t] + red[1][t] + red[2][t] + red[3][t]
                         + mab_bv[4*128 + t];
    __syncthreads();
    float mv = matvec_qs(mab_Wo + 4*16384, Ovec, red, t);
    if (t < 128) S1[t] = Ovec[t] + fmaxf(mv + mab_bo[4*128 + t], 0.f);
    __syncthreads();
    float q5 = matvec_qs(mab_Wq + 5*16384, S1, red, t);
    float v5 = matvec_qs(mab_Wv + 5*16384, S1, red, t);
    if (t < 128) S2[t] = q5 + mab_bq[5*128 + t] + v5 + mab_bv[5*128 + t];
    __syncthreads();
    float m5 = matvec_qs(mab_Wo + 5*16384, S2, red, t);
    if (t < 128) S1[t] = S2[t] + fmaxf(m5 + mab_bo[5*128 + t], 0.f);
    __syncthreads();
    float q6 = matvec_qs(mab_Wq + 6*16384, S1, red, t);
    float v6 = matvec_qs(mab_Wv + 6*16384, S1, red, t);
    if (t < 128) S2[t] = q6 + mab_bq[6*128 + t] + v6 + mab_bv[6*128 + t];
    __syncthreads();
    float m6 = matvec_qs(mab_Wo + 6*16384, S2, red, t);
    if (t < 128) S1[t] = S2[t] + fmaxf(m6 + mab_bo[6*128 + t], 0.f);
    __syncthreads();
    float y = matvec_qs(dec_W, S1, red, t);
    if (t < 128) out[b*768 + t] = y + dec_b[t];
    {
        int p = t >> 7, c = t & 127;
        out[b*768 + (1 + p)*128 + c] = protos[p*128 + c];
        if (t < 128) out[b*768 + 640 + t] = protos[512 + t];
    }
}

extern "C" void kernel_launch(void* const* d_in, const int* in_sizes, int n_in,
                              void* d_out, int out_size, void* d_ws, size_t ws_size,
                              hipStream_t stream)
{
    (void)in_sizes; (void)n_in; (void)out_size; (void)ws_size;
    const int*   node_ids  = (const int*)d_in[0];
    const int*   edge_idx  = (const int*)d_in[1];
    const float* node_embed= (const float*)d_in[3];
    const float* lin_W     = (const float*)d_in[4];
    const float* lin_b     = (const float*)d_in[5];
    const float* gat_W     = (const float*)d_in[6];
    const float* att_src   = (const float*)d_in[7];
    const float* att_dst   = (const float*)d_in[8];
    const float* gat_bias  = (const float*)d_in[9];
    const float* mab_Wq    = (const float*)d_in[10];
    const float* mab_bq    = (const float*)d_in[11];
    const float* mab_Wk    = (const float*)d_in[12];
    const float* mab_bk    = (const float*)d_in[13];
    const float* mab_Wv    = (const float*)d_in[14];
    const float* mab_bv    = (const float*)d_in[15];
    const float* mab_Wo    = (const float*)d_in[16];
    const float* mab_bo    = (const float*)d_in[17];
    const float* isab_I    = (const float*)d_in[18];
    const float* pma_S     = (const float*)d_in[19];
    const float* dec_W     = (const float*)d_in[20];
    const float* dec_b     = (const float*)d_in[21];
    const float* protos    = (const float*)d_in[22];

    float* ws    = (float*)d_ws;
    float* X     = ws + OFF_X;
    float* acc   = ws + OFF_ACC;
    float* X2    = ws + OFF_X2;
    float* qp    = ws + OFF_QP;
    float* wkh   = ws + OFF_WKH;
    float* ckh   = ws + OFF_CKH;
    float* vas   = ws + OFF_VAS;
    float* vad   = ws + OFF_VAD;
    float* bfin  = ws + OFF_BFIN;
    float* csd   = ws + OFF_CSD;
    float* upA   = ws + OFF_UPA;
    float* spA   = ws + OFF_SPA;
    float* upB   = ws + OFF_UPB;
    float* spB   = ws + OFF_SPB;
    unsigned short* pWh = (unsigned short*)(ws + OFF_PWH);
    unsigned short* pWl = (unsigned short*)(ws + OFF_PWL);
    int*   mask  = (int*)(ws + OFF_MASK);
    int*   cnt   = (int*)(ws + OFF_CNT);
    int*   deg   = (int*)(ws + OFF_DEG);
    int*   fill  = (int*)(ws + OFF_FILL);
    int*   map   = (int*)(ws + OFF_MAP);
    int*   inv   = (int*)(ws + OFF_INV);
    int*   rowp  = (int*)(ws + OFF_ROWPTR);
    int*   colx  = (int*)(ws + OFF_COL);
    float* out   = (float*)d_out;

    hipMemsetAsync(ws + OFF_MASK, 0, ZERO_BYTES, stream);

    prep_all_kernel<<<354, 256, 0, stream>>>(lin_W, lin_b, gat_W, mab_Wq, mab_bq, mab_Wk,
                                             mab_bk, mab_Wo, att_src, att_dst, gat_bias,
                                             isab_I, pma_S, node_ids,
                                             pWh, pWl, qp, wkh, ckh, vas, vad, bfin, csd, mask);
    assign_kernel<<<(N_NODES + 255)/256, 256, 0, stream>>>(mask, map, inv, cnt, deg, fill);
    pass1_kernel<<<(N_ITEMS + 255)/256, 256, 0, stream>>>(edge_idx, map, deg);
    scan_kernel<<<1, 256, 0, stream>>>(deg, rowp);
    pass2_kernel<<<(N_ITEMS + 255)/256, 256, 0, stream>>>(edge_idx, map, rowp, fill, colx);
    agg_kernel<<<NROWS/4, 256, 0, stream>>>(rowp, colx, inv, cnt, vas, vad, csd,
                                            node_embed, acc);
    mfma_lin_kernel<<<NROWS/64, 256, 0, stream>>>(acc, pWh, pWl, bfin, X2);
    gatherA_kernel<<<NROWS/64, 256, 0, stream>>>(node_ids, map, X2, wkh, ckh, X, upA, spA);

    // odd MAB 1 (inline evenB of mab0 from upA) -> partials for mab2 in upB
    odd_fused_kernel<<<NROWS/64, 256, 0, stream>>>(X, upA, spA, qp,
                                                   mab_Wv, mab_bv, mab_Wo, mab_bo,
                                                   pWh + 1*16384, pWl + 1*16384, mab_bq + 128,
                                                   pWh + 2*16384, pWl + 2*16384, mab_bo + 128,
                                                   mab_Wv + 16384, mab_bv + 128,
                                                   wkh + 512, ckh + 4,
                                                   X, upB, spB);
    // odd MAB 3 (inline evenB of mab2 from upB) -> partials for mab4 in upA
    odd_fused_kernel<<<NROWS/64, 256, 0, stream>>>(X, upB, spB, qp + 128,
                                                   mab_Wv + 2*16384, mab_bv + 2*128,
                                                   mab_Wo + 2*16384, mab_bo + 2*128,
                                                   pWh + 3*16384, pWl + 3*16384, mab_bq + 3*128,
                                                   pWh + 4*16384, pWl + 4*16384, mab_bo + 3*128,
                                                   mab_Wv + 3*16384, mab_bv + 3*128,
                                                   wkh + 1024, ckh + 8,
                                                   X, upA, spA);
    attn_pmaB_kernel<<<16, 512, 0, stream>>>(upA, spA, qp + 256,
                                             mab_Wq, mab_bq, mab_Wv, mab_bv, mab_Wo, mab_bo,
                                             dec_W, dec_b, protos, out);
}